// Round 13
// baseline (168.500 us; speedup 1.0000x reference)
//
#include <hip/hip_runtime.h>

typedef __attribute__((ext_vector_type(8))) short short8;
typedef __attribute__((ext_vector_type(4))) float f32x4;

#define SGC (-1.44269504088896341f)   /* -log2(e): sigmoid prescale */
#define THC ( 2.88539008177792681f)   /* 2*log2(e): tanh prescale   */

__device__ __forceinline__ unsigned short f2bf(float f){
  unsigned u = __float_as_uint(f);
  return (unsigned short)((u + 0x7fffu + ((u >> 16) & 1u)) >> 16);
}
__device__ __forceinline__ float bf2f(unsigned short b){
  return __uint_as_float(((unsigned)b) << 16);
}
__device__ __forceinline__ unsigned f2bf_cvt(float f){
  unsigned r;
  asm("v_cvt_pk_bf16_f32 %0, %1, %1" : "=v"(r) : "v"(f));
  return r;
}
__device__ __forceinline__ unsigned f2bf_pk(float lo, float hi){
  unsigned r;
  asm("v_cvt_pk_bf16_f32 %0, %1, %2" : "=v"(r) : "v"(lo), "v"(hi));
  return r;
}

// wgt layout v13 (u16 elems) — only weights needed by k_mlp12 / k_head:
//   W1b  [128*96]   @0       (96 = 68 padded, zeros)
//   W2b  [128*128]  @12288
//   Wf1b [256*1152] @28672
//   Wf2b [128*256]  @323584
//   Wf3b [64*128]   @356352   (total 364544)

// ---------------- mega-kernel: gru_t | prep | gru_n ----------------
// blocks 0..127: target GRU (self-converting weights from Whh_t fp32)
// blocks 128..1551: fp32->bf16 prep of W1/W2/Wf1/Wf2/Wf3 (for later launches)
// blocks 1552..3599: neighbor GRU (col-wave, self-converting) + pooling
__global__ __launch_bounds__(256) void k_main(
    const float* __restrict__ ttraj, const float* __restrict__ ntraj,
    const float* __restrict__ rang,  const float* __restrict__ nmask,
    const float* __restrict__ Wih_n, const float* __restrict__ bih_n,
    const float* __restrict__ bhh_n, const float* __restrict__ Whh_n,
    const float* __restrict__ Wih_t, const float* __restrict__ bih_t,
    const float* __restrict__ bhh_t, const float* __restrict__ Whh_t,
    const float* __restrict__ W1,    const float* __restrict__ W2,
    const float* __restrict__ Wf1,   const float* __restrict__ Wf2,
    const float* __restrict__ Wf3,
    unsigned short* __restrict__ wgt,
    unsigned short* __restrict__ sf,            // [16384][96] bf16
    unsigned short* __restrict__ combined)      // [2048][1152] bf16
{
  __shared__ char smem[11264];
  const int tid = threadIdx.x;
  const int w = tid >> 6, u = (tid >> 4) & 3, c = tid & 15;
  const f32x4 zz = {0.f,0.f,0.f,0.f};

  if (blockIdx.x >= 1552){
    // ================= neighbor GRU (col-wave) + pooling =================
    const int b = blockIdx.x - 1552;
    unsigned short* hbuf = (unsigned short*)smem;             // [64][72]
    unsigned* xpk = (unsigned*)(smem + 9216);                 // [8][64] u32
    float* pool   = (float*)(smem + 9216);                    // alias

    // self-convert step-invariant B fragments (prescaled) from fp32
    short8 Bh[6], Bx[3];
#pragma unroll
    for (int k = 0; k < 3; ++k){           // 0=r, 1=z, 2=n
      float s = (k < 2) ? SGC : THC;
      const float* src = Whh_n + ((size_t)((k*4 + w)*16 + c))*64;
#pragma unroll
      for (int h = 0; h < 2; ++h){
        const float* p = src + h*32 + u*8;
        union { unsigned ui[4]; short8 s8; } t;
#pragma unroll
        for (int j = 0; j < 4; ++j) t.ui[j] = f2bf_pk(p[2*j]*s, p[2*j+1]*s);
        Bh[k*2+h] = t.s8;
      }
      int g = k*64 + w*16 + c;
      float bsum = ((k < 2) ? (bih_n[g] + bhh_n[g]) : bih_n[g]);
      union { unsigned ui[4]; short8 s8; } tx;
      tx.ui[0] = f2bf_pk(Wih_n[g*2]*s, Wih_n[g*2+1]*s);
      tx.ui[1] = f2bf_pk(bsum*s, 0.f);
      tx.ui[2] = 0u; tx.ui[3] = 0u;
      Bx[k] = tx.s8;
    }
    const float bh_ = bhh_n[128 + w*16 + c] * THC;

    // stage trajectories packed bf16: xpk[step][seq]
    {
      float4 v = ((const float4*)(ntraj + (size_t)b * 1024))[tid];
      int n = tid >> 2, p = (tid & 3) * 2;
      xpk[p*64 + n]     = f2bf_pk(v.x, v.y);
      xpk[(p+1)*64 + n] = f2bf_pk(v.z, v.w);
    }
    __syncthreads();

    float hcur[4][4];
#pragma unroll
    for (int sg=0; sg<4; ++sg)
#pragma unroll
      for (int q=0; q<4; ++q) hcur[sg][q] = 0.0f;

#pragma unroll 1
    for (int st = 0; st < 8; ++st){
      short8 a0s[4], a1s[4];
      unsigned xv[4];
#pragma unroll
      for (int sg = 0; sg < 4; ++sg){
        xv[sg] = xpk[st*64 + sg*16 + c];
        if (st > 0){
          a0s[sg] = *(short8*)&hbuf[(sg*16 + c)*72 + u*8];
          a1s[sg] = *(short8*)&hbuf[(sg*16 + c)*72 + 32 + u*8];
        }
      }
      __syncthreads();

#pragma unroll
      for (int sg = 0; sg < 4; ++sg){
        union { unsigned ui[4]; short8 s8; } a2u;
        a2u.ui[0] = (u == 0) ? xv[sg] : 0u;
        a2u.ui[1] = (u == 0) ? 0x3F80u : 0u;
        a2u.ui[2] = 0u; a2u.ui[3] = 0u;
        short8 a2 = a2u.s8;

        f32x4 aR = __builtin_amdgcn_mfma_f32_16x16x32_bf16(a2, Bx[0], zz, 0,0,0);
        f32x4 aZ = __builtin_amdgcn_mfma_f32_16x16x32_bf16(a2, Bx[1], zz, 0,0,0);
        f32x4 aX = __builtin_amdgcn_mfma_f32_16x16x32_bf16(a2, Bx[2], zz, 0,0,0);
        f32x4 aN = zz;
        if (st > 0){
          aR = __builtin_amdgcn_mfma_f32_16x16x32_bf16(a0s[sg], Bh[0], aR, 0,0,0);
          aR = __builtin_amdgcn_mfma_f32_16x16x32_bf16(a1s[sg], Bh[1], aR, 0,0,0);
          aZ = __builtin_amdgcn_mfma_f32_16x16x32_bf16(a0s[sg], Bh[2], aZ, 0,0,0);
          aZ = __builtin_amdgcn_mfma_f32_16x16x32_bf16(a1s[sg], Bh[3], aZ, 0,0,0);
          aN = __builtin_amdgcn_mfma_f32_16x16x32_bf16(a0s[sg], Bh[4], aN, 0,0,0);
          aN = __builtin_amdgcn_mfma_f32_16x16x32_bf16(a1s[sg], Bh[5], aN, 0,0,0);
        }
#pragma unroll
        for (int q = 0; q < 4; ++q){
          float r = __builtin_amdgcn_rcpf(1.0f + __builtin_amdgcn_exp2f(aR[q]));
          float z = __builtin_amdgcn_rcpf(1.0f + __builtin_amdgcn_exp2f(aZ[q]));
          float hn = aN[q] + bh_;
          float pn = __builtin_fmaf(r, hn, aX[q]);
          float E = __builtin_amdgcn_exp2f(pn);
          float n = __builtin_fmaf(-2.0f, __builtin_amdgcn_rcpf(E + 1.0f), 1.0f);
          float hnew = __builtin_fmaf(z, hcur[sg][q] - n, n);
          hcur[sg][q] = hnew;
          hbuf[(sg*16 + u*4 + q)*72 + w*16 + c] = (unsigned short)f2bf_cvt(hnew);
        }
      }
      __syncthreads();
    }

    // ---- sector pooling ----
    if (tid < 64){
      int n = tid;
      const float* nb = ntraj + (size_t)b*1024 + n*16;
      float px = nb[14], py = nb[15];
      float vx = px - nb[12], vy = py - nb[13];
      float m   = nmask[(size_t)b*64 + n];
      float ang = rang[(size_t)b*64 + n];
      float tx = ttraj[(size_t)b*16 + 14], ty = ttraj[(size_t)b*16 + 15];
      float dx = px - tx, dy = py - ty;
      float dist = __builtin_amdgcn_sqrtf(dx*dx + dy*dy);
      int sid = (int)(ang / 0.78539816339744830962f);
      sid = sid < 0 ? 0 : (sid > 7 ? 7 : sid);
      bool valid = m > 0.0f;
      float wv = valid ? __builtin_amdgcn_exp2f(dist * -0.14426950408889634f) : 0.0f;
      pool[n]       = valid ? dist : 0.0f;
      pool[64 + n]  = valid ? vx   : 0.0f;
      pool[128 + n] = valid ? vy   : 0.0f;
      pool[192 + n] = wv;
      pool[256 + n] = valid ? (float)sid : -1.0f;
    }
    __syncthreads();
    if (tid < 8){
      int s = tid;
      float cnt=0.f, sd=0.f, sx=0.f, sy=0.f, sw=0.f;
#pragma unroll 4
      for (int n=0; n<64; ++n){
        if (pool[256+n] == (float)s){
          cnt += 1.f; sd += pool[n]; sx += pool[64+n]; sy += pool[128+n]; sw += pool[192+n];
        }
      }
      float inv = (cnt > 0.f) ? __builtin_amdgcn_rcpf(cnt) : 0.f;
      pool[320 + s] = cnt;
      pool[328 + s] = sd * inv;
      pool[336 + s] = sx * inv;
      pool[344 + s] = sy * inv;
      pool[352 + s] = __builtin_amdgcn_rcpf(sw + 1e-8f);
    }
    __syncthreads();
#pragma unroll
    for (int rep = 0; rep < 2; ++rep){
      int p = tid + rep*256;
      int s = p >> 6, h = p & 63;
      float fs = (float)s;
      float a = 0.f;
#pragma unroll 4
      for (int n = 0; n < 64; ++n){
        float wmv = (pool[256+n] == fs) ? pool[192+n] : 0.f;
        float nf  = bf2f(hbuf[n*72 + h]);
        a += wmv * nf;
      }
      sf[((size_t)b*8 + s)*96 + 4 + h] = (unsigned short)f2bf_cvt(a * pool[352+s]);
    }
    if (tid < 32){
      int s = tid >> 2, cc = tid & 3;
      sf[((size_t)b*8 + s)*96 + cc] = (unsigned short)f2bf_cvt(pool[320 + cc*8 + s]);
    }
    if (tid < 224){
      int s = tid / 28, cc = 68 + tid % 28;
      sf[((size_t)b*8 + s)*96 + cc] = 0;
    }

  } else if (blockIdx.x >= 128){
    // ================= prep: fp32 -> bf16 for mlp/head weights =================
    int i = (blockIdx.x - 128) * 256 + tid;
    if (i < 12288){ int r = i / 96, cc = i % 96;
      wgt[i] = (cc < 68) ? f2bf(W1[r*68 + cc]) : (unsigned short)0; return; }
    i -= 12288;
    if (i < 16384){ wgt[12288 + i] = f2bf(W2[i]); return; }
    i -= 16384;
    if (i < 294912){ wgt[28672 + i] = f2bf(Wf1[i]); return; }
    i -= 294912;
    if (i < 32768){ wgt[323584 + i] = f2bf(Wf2[i]); return; }
    i -= 32768;
    if (i < 8192){ wgt[356352 + i] = f2bf(Wf3[i]); return; }

  } else {
    // ================= target GRU (self-converting weights) =================
    const int bt = blockIdx.x;
    unsigned short* hb0 = (unsigned short*)smem;             // [16][136]
    unsigned short* hb1 = (unsigned short*)(smem + 4352);    // [16][136]
    float* xs = (float*)(smem + 8704);                       // [16][16]

    xs[tid] = ttraj[(size_t)bt*256 + tid];

    int ntg[6];
    ntg[0] = 2*w; ntg[1] = 2*w+1;
    ntg[2] = 8+2*w; ntg[3] = 9+2*w;
    ntg[4] = 16+2*w; ntg[5] = 17+2*w;

    short8 Bf[6][4];
#pragma unroll
    for (int lt2 = 0; lt2 < 6; ++lt2){
      float s = (lt2 < 4) ? SGC : THC;             // ntg<16 -> r,z rows
      const float* wp = Whh_t + (size_t)(ntg[lt2]*16 + c)*128 + u*8;
#pragma unroll
      for (int kk = 0; kk < 4; ++kk){
        const float* p = wp + kk*32;
        union { unsigned ui[4]; short8 s8; } t;
#pragma unroll
        for (int j = 0; j < 4; ++j) t.ui[j] = f2bf_pk(p[2*j]*s, p[2*j+1]*s);
        Bf[lt2][kk] = t.s8;
      }
    }

    float Wr0[2],Wr1[2],BR[2],Wz0[2],Wz1[2],BZ[2],Wn0[2],Wn1[2],BI[2],BH[2];
#pragma unroll
    for (int gt = 0; gt < 2; ++gt){
      int g = w*32 + gt*16 + c;
      Wr0[gt]=Wih_t[g*2]*SGC;        Wr1[gt]=Wih_t[g*2+1]*SGC;        BR[gt]=(bih_t[g]+bhh_t[g])*SGC;
      Wz0[gt]=Wih_t[(128+g)*2]*SGC;  Wz1[gt]=Wih_t[(128+g)*2+1]*SGC;  BZ[gt]=(bih_t[128+g]+bhh_t[128+g])*SGC;
      Wn0[gt]=Wih_t[(256+g)*2]*THC;  Wn1[gt]=Wih_t[(256+g)*2+1]*THC;  BI[gt]=bih_t[256+g]*THC; BH[gt]=bhh_t[256+g]*THC;
    }
    float hcur[2][4];
#pragma unroll
    for (int gt=0; gt<2; ++gt)
#pragma unroll
      for (int q=0; q<4; ++q) hcur[gt][q] = 0.0f;
    __syncthreads();

#pragma unroll 1
    for (int st = 0; st < 8; ++st){
      unsigned short* rbuf = (st & 1) ? hb0 : hb1;
      unsigned short* wbuf = (st & 1) ? hb1 : hb0;
      f32x4 acc[6];
      if (st > 0){
        short8 a0 = *(short8*)&rbuf[c*136 + u*8];
        short8 a1 = *(short8*)&rbuf[c*136 + 32 + u*8];
        short8 a2 = *(short8*)&rbuf[c*136 + 64 + u*8];
        short8 a3 = *(short8*)&rbuf[c*136 + 96 + u*8];
#pragma unroll
        for (int lt2 = 0; lt2 < 6; ++lt2){
          f32x4 t = {0.f,0.f,0.f,0.f};
          t = __builtin_amdgcn_mfma_f32_16x16x32_bf16(a0, Bf[lt2][0], t, 0,0,0);
          t = __builtin_amdgcn_mfma_f32_16x16x32_bf16(a1, Bf[lt2][1], t, 0,0,0);
          t = __builtin_amdgcn_mfma_f32_16x16x32_bf16(a2, Bf[lt2][2], t, 0,0,0);
          acc[lt2] = __builtin_amdgcn_mfma_f32_16x16x32_bf16(a3, Bf[lt2][3], t, 0,0,0);
        }
      } else {
#pragma unroll
        for (int lt2 = 0; lt2 < 6; ++lt2) acc[lt2] = (f32x4){0.f,0.f,0.f,0.f};
      }
#pragma unroll
      for (int gt = 0; gt < 2; ++gt){
#pragma unroll
        for (int q = 0; q < 4; ++q){
          int sq = u*4 + q;
          float x0 = xs[sq*16 + st*2], x1 = xs[sq*16 + st*2 + 1];
          float rp = __builtin_fmaf(Wr0[gt], x0, __builtin_fmaf(Wr1[gt], x1, acc[gt][q] + BR[gt]));
          float zp = __builtin_fmaf(Wz0[gt], x0, __builtin_fmaf(Wz1[gt], x1, acc[2+gt][q] + BZ[gt]));
          float r = __builtin_amdgcn_rcpf(1.0f + __builtin_amdgcn_exp2f(rp));
          float z = __builtin_amdgcn_rcpf(1.0f + __builtin_amdgcn_exp2f(zp));
          float hnv = acc[4+gt][q] + BH[gt];
          float pn = __builtin_fmaf(Wn0[gt], x0, __builtin_fmaf(Wn1[gt], x1, __builtin_fmaf(r, hnv, BI[gt])));
          float E = __builtin_amdgcn_exp2f(pn);
          float n = __builtin_fmaf(-2.0f, __builtin_amdgcn_rcpf(E + 1.0f), 1.0f);
          float hnew = __builtin_fmaf(z, hcur[gt][q] - n, n);
          hcur[gt][q] = hnew;
          if (st < 7){
            wbuf[sq*136 + w*32 + gt*16 + c] = (unsigned short)f2bf_cvt(hnew);
          } else {
            int row = bt*16 + sq;
            combined[(size_t)row*1152 + w*32 + gt*16 + c] = (unsigned short)f2bf_cvt(hnew);
          }
        }
      }
      if (st < 7) __syncthreads();
    }
  }
}

// ---------------- MLP1/MLP2 over (b,s) rows: sf -> enc part of combined ----------------
__global__ __launch_bounds__(256) void k_mlp12(
    const unsigned short* __restrict__ sf,    // [16384][96]
    const unsigned short* __restrict__ wgt,
    const float* __restrict__ b1, const float* __restrict__ b2,
    unsigned short* __restrict__ combined)
{
  __shared__ char smem[18432];
  unsigned short* hb = (unsigned short*)smem + (threadIdx.x >> 6) * 2176;  // [16][136]/wave
  float* b1s = (float*)(smem + 17408);
  float* b2s = b1s + 128;
  const unsigned short* w1b = wgt;            // [128][96]
  const unsigned short* w2b = wgt + 12288;    // [128][128]
  const int tid = threadIdx.x, w = tid >> 6, u = (tid >> 4) & 3, c = tid & 15;
  if (tid < 128){ b1s[tid] = b1[tid]; b2s[tid] = b2[tid]; }
  __syncthreads();
  const int rowb = blockIdx.x * 64 + w * 16;

  f32x4 acc[8];
#pragma unroll
  for (int nt=0; nt<8; ++nt) acc[nt] = (f32x4){0.f,0.f,0.f,0.f};
#pragma unroll
  for (int kc=0; kc<3; ++kc){
    short8 a = *(const short8*)&sf[(size_t)(rowb + c)*96 + kc*32 + u*8];
#pragma unroll
    for (int nt=0; nt<8; ++nt){
      short8 bb = *(const short8*)&w1b[(nt*16+c)*96 + kc*32 + u*8];
      acc[nt] = __builtin_amdgcn_mfma_f32_16x16x32_bf16(a, bb, acc[nt], 0,0,0);
    }
  }
#pragma unroll
  for (int nt=0; nt<8; ++nt){
    float bias = b1s[nt*16+c];
#pragma unroll
    for (int q=0; q<4; ++q){
      float v = acc[nt][q] + bias; v = v > 0.f ? v : 0.f;
      hb[(u*4+q)*136 + nt*16 + c] = (unsigned short)f2bf_cvt(v);
    }
  }
  f32x4 acc2[8];
#pragma unroll
  for (int nt=0; nt<8; ++nt) acc2[nt] = (f32x4){0.f,0.f,0.f,0.f};
#pragma unroll
  for (int kc=0; kc<4; ++kc){
    short8 a = *(short8*)&hb[c*136 + kc*32 + u*8];
#pragma unroll
    for (int nt=0; nt<8; ++nt){
      short8 bb = *(const short8*)&w2b[(nt*16+c)*128 + kc*32 + u*8];
      acc2[nt] = __builtin_amdgcn_mfma_f32_16x16x32_bf16(a, bb, acc2[nt], 0,0,0);
    }
  }
#pragma unroll
  for (int nt=0; nt<8; ++nt){
    float bias = b2s[nt*16+c];
#pragma unroll
    for (int q=0; q<4; ++q){
      float v = acc2[nt][q] + bias; v = v > 0.f ? v : 0.f;
      int r = rowb + u*4 + q;
      combined[(size_t)(r >> 3)*1152 + 128 + (r & 7)*128 + nt*16 + c] = (unsigned short)f2bf_cvt(v);
    }
  }
}

// ---------------- head: 128 blocks x 256 thr (4 waves) ----------------
__global__ __launch_bounds__(256) void k_head(
    const unsigned short* __restrict__ combined,
    const unsigned short* __restrict__ wgt,
    const float* __restrict__ bf1, const float* __restrict__ bf2, const float* __restrict__ bf3,
    const float* __restrict__ lng, const float* __restrict__ lnb,
    float* __restrict__ out)
{
  __shared__ char smem[15104];
  const int tid = threadIdx.x, w = tid >> 6, u = (tid >> 4) & 3, c = tid & 15;
  unsigned short* f1b = (unsigned short*)smem;                 // [16][264]
  unsigned short* f2b = (unsigned short*)(smem + 8448);        // [16][136]
  float* bf1s = (float*)(smem + 12800); float* bf2s = (float*)(smem + 13824);
  float* bf3s = (float*)(smem + 14336);
  float* lngs = (float*)(smem + 14592); float* lnbs = (float*)(smem + 14848);
  const unsigned short* wf1b = wgt + 28672;
  const unsigned short* wf2b = wgt + 323584;
  const unsigned short* wf3b = wgt + 356352;
  bf1s[tid] = bf1[tid];
  if (tid < 128) bf2s[tid] = bf2[tid];
  if (tid < 64){ bf3s[tid] = bf3[tid]; lngs[tid] = lng[tid]; lnbs[tid] = lnb[tid]; }
  __syncthreads();
  const int rowb = blockIdx.x * 16;

  f32x4 acc[4];
#pragma unroll
  for (int i=0; i<4; ++i) acc[i] = (f32x4){0.f,0.f,0.f,0.f};
#pragma unroll 4
  for (int kc=0; kc<36; ++kc){
    short8 a = *(const short8*)&combined[(size_t)(rowb + c)*1152 + kc*32 + u*8];
#pragma unroll
    for (int i=0; i<4; ++i){
      int nt = w*4 + i;
      short8 bb = *(const short8*)&wf1b[(size_t)(nt*16+c)*1152 + kc*32 + u*8];
      acc[i] = __builtin_amdgcn_mfma_f32_16x16x32_bf16(a, bb, acc[i], 0,0,0);
    }
  }
#pragma unroll
  for (int i=0; i<4; ++i){
    int nt = w*4 + i;
    float bias = bf1s[nt*16+c];
#pragma unroll
    for (int q=0; q<4; ++q){
      float v = acc[i][q] + bias; v = v > 0.f ? v : 0.f;
      f1b[(u*4+q)*264 + nt*16 + c] = (unsigned short)f2bf_cvt(v);
    }
  }
  __syncthreads();

  f32x4 acc2[2];
#pragma unroll
  for (int i=0; i<2; ++i) acc2[i] = (f32x4){0.f,0.f,0.f,0.f};
#pragma unroll
  for (int kc=0; kc<8; ++kc){
    short8 a = *(short8*)&f1b[c*264 + kc*32 + u*8];
#pragma unroll
    for (int i=0; i<2; ++i){
      int nt = w*2 + i;
      short8 bb = *(const short8*)&wf2b[(nt*16+c)*256 + kc*32 + u*8];
      acc2[i] = __builtin_amdgcn_mfma_f32_16x16x32_bf16(a, bb, acc2[i], 0,0,0);
    }
  }
#pragma unroll
  for (int i=0; i<2; ++i){
    int nt = w*2 + i;
    float bias = bf2s[nt*16+c];
#pragma unroll
    for (int q=0; q<4; ++q){
      float v = acc2[i][q] + bias; v = v > 0.f ? v : 0.f;
      f2b[(u*4+q)*136 + nt*16 + c] = (unsigned short)f2bf_cvt(v);
    }
  }
  __syncthreads();

  f32x4 acc3[4];
#pragma unroll
  for (int nt=0; nt<4; ++nt) acc3[nt] = (f32x4){0.f,0.f,0.f,0.f};
#pragma unroll
  for (int kc=0; kc<4; ++kc){
    short8 a = *(short8*)&f2b[c*136 + kc*32 + u*8];
#pragma unroll
    for (int nt=0; nt<4; ++nt){
      short8 bb = *(const short8*)&wf3b[(nt*16+c)*128 + kc*32 + u*8];
      acc3[nt] = __builtin_amdgcn_mfma_f32_16x16x32_bf16(a, bb, acc3[nt], 0,0,0);
    }
  }
  if (w == 0){
    float v[4][4];
#pragma unroll
    for (int nt=0; nt<4; ++nt){
      float bias = bf3s[nt*16+c];
#pragma unroll
      for (int q=0; q<4; ++q){
        float t = acc3[nt][q] + bias; v[nt][q] = t > 0.f ? t : 0.f;
      }
    }
#pragma unroll
    for (int q=0; q<4; ++q){
      float p = v[0][q] + v[1][q] + v[2][q] + v[3][q];
      p += __shfl_xor(p, 1); p += __shfl_xor(p, 2); p += __shfl_xor(p, 4); p += __shfl_xor(p, 8);
      float mu = p * 0.015625f;
      float d0 = v[0][q]-mu, d1 = v[1][q]-mu, d2 = v[2][q]-mu, d3 = v[3][q]-mu;
      float p2 = d0*d0 + d1*d1 + d2*d2 + d3*d3;
      p2 += __shfl_xor(p2, 1); p2 += __shfl_xor(p2, 2); p2 += __shfl_xor(p2, 4); p2 += __shfl_xor(p2, 8);
      float rstd = __builtin_amdgcn_rsqf(p2 * 0.015625f + 1e-5f);
      int row = rowb + u*4 + q;
#pragma unroll
      for (int nt=0; nt<4; ++nt){
        int col = nt*16 + c;
        out[(size_t)row*64 + col] = (v[nt][q] - mu) * rstd * lngs[col] + lnbs[col];
      }
    }
  }
}

extern "C" void kernel_launch(void* const* d_in, const int* in_sizes, int n_in,
                              void* d_out, int out_size, void* d_ws, size_t ws_size,
                              hipStream_t stream)
{
  const float* ttraj = (const float*)d_in[0];
  const float* ntraj = (const float*)d_in[1];
  const float* rang  = (const float*)d_in[2];
  const float* nmask = (const float*)d_in[3];
  const float* Wih_t = (const float*)d_in[4];
  const float* Whh_t = (const float*)d_in[5];
  const float* bih_t = (const float*)d_in[6];
  const float* bhh_t = (const float*)d_in[7];
  const float* Wih_n = (const float*)d_in[8];
  const float* Whh_n = (const float*)d_in[9];
  const float* bih_n = (const float*)d_in[10];
  const float* bhh_n = (const float*)d_in[11];
  const float* W1  = (const float*)d_in[12];
  const float* b1  = (const float*)d_in[13];
  const float* W2  = (const float*)d_in[14];
  const float* b2  = (const float*)d_in[15];
  const float* Wf1 = (const float*)d_in[16];
  const float* bf1 = (const float*)d_in[17];
  const float* Wf2 = (const float*)d_in[18];
  const float* bf2 = (const float*)d_in[19];
  const float* Wf3 = (const float*)d_in[20];
  const float* bf3 = (const float*)d_in[21];
  const float* lng = (const float*)d_in[22];
  const float* lnb = (const float*)d_in[23];

  char* ws = (char*)d_ws;
  unsigned short* combined = (unsigned short*)ws;                  // [2048][1152] bf16
  unsigned short* sf       = (unsigned short*)(ws + 5242880);      // [16384][96] bf16
  unsigned short* wgt      = (unsigned short*)(ws + 8388608);      // bf16 weights (364544 u16)

  hipLaunchKernelGGL(k_main, dim3(3600), dim3(256), 0, stream,
                     ttraj, ntraj, rang, nmask,
                     Wih_n, bih_n, bhh_n, Whh_n,
                     Wih_t, bih_t, bhh_t, Whh_t,
                     W1, W2, Wf1, Wf2, Wf3,
                     wgt, sf, combined);
  hipLaunchKernelGGL(k_mlp12, dim3(256), dim3(256), 0, stream, sf, wgt, b1, b2, combined);
  hipLaunchKernelGGL(k_head, dim3(128), dim3(256), 0, stream,
                     combined, wgt, bf1, bf2, bf3, lng, lnb, (float*)d_out);
}

// Round 14
// 146.154 us; speedup vs baseline: 1.1529x; 1.1529x over previous
//
#include <hip/hip_runtime.h>

typedef __attribute__((ext_vector_type(8))) short short8;
typedef __attribute__((ext_vector_type(4))) float f32x4;

#define SGC (-1.44269504088896341f)   /* -log2(e): sigmoid prescale */
#define THC ( 2.88539008177792681f)   /* 2*log2(e): tanh prescale   */

__device__ __forceinline__ unsigned short f2bf(float f){
  unsigned u = __float_as_uint(f);
  return (unsigned short)((u + 0x7fffu + ((u >> 16) & 1u)) >> 16);
}
__device__ __forceinline__ float bf2f(unsigned short b){
  return __uint_as_float(((unsigned)b) << 16);
}
__device__ __forceinline__ unsigned f2bf_cvt(float f){
  unsigned r;
  asm("v_cvt_pk_bf16_f32 %0, %1, %1" : "=v"(r) : "v"(f));
  return r;
}
__device__ __forceinline__ unsigned f2bf_pk(float lo, float hi){
  unsigned r;
  asm("v_cvt_pk_bf16_f32 %0, %1, %2" : "=v"(r) : "v"(lo), "v"(hi));
  return r;
}

// ---------------- weight conversion: fp32 -> bf16 in ws ----------------
// wgt layout (u16 elems):
//   whhT_b [384*128]  @0        (PRESCALED: rows<256 *SGC, rows>=256 *THC)
//   W1b    [128*96]   @49152    (96 = 68 padded, zeros)
//   W2b    [128*128]  @61440
//   Wf1b   [256*1152] @77824
//   Wf2b   [128*256]  @372736
//   Wf3b   [64*128]   @405504
//   whhN_b [192*64]   @413696   (PRESCALED: rows<128 *SGC, rows>=128 *THC)
//   wxg    [12*16*8]  @425984   (x-proj tiles: j0=W0*s, j1=W1*s, j2=bias*s)
__global__ __launch_bounds__(256) void k_prep(
    const float* __restrict__ Whh_t, const float* __restrict__ W1,
    const float* __restrict__ W2,    const float* __restrict__ Wf1,
    const float* __restrict__ Wf2,   const float* __restrict__ Wf3,
    const float* __restrict__ Whh_n, const float* __restrict__ Wih_n,
    const float* __restrict__ bih_n, const float* __restrict__ bhh_n,
    unsigned short* __restrict__ wgt)
{
  int i = blockIdx.x * 256 + threadIdx.x;
  if (i < 49152){
    int g = i >> 7;
    float s = (g < 256) ? SGC : THC;
    wgt[i] = f2bf(Whh_t[i] * s); return;
  }
  i -= 49152;
  if (i < 12288){ int r = i / 96, c = i % 96;
    wgt[49152 + i] = (c < 68) ? f2bf(W1[r*68 + c]) : (unsigned short)0; return; }
  i -= 12288;
  if (i < 16384){ wgt[61440 + i] = f2bf(W2[i]); return; }
  i -= 16384;
  if (i < 294912){ wgt[77824 + i] = f2bf(Wf1[i]); return; }
  i -= 294912;
  if (i < 32768){ wgt[372736 + i] = f2bf(Wf2[i]); return; }
  i -= 32768;
  if (i < 8192){ wgt[405504 + i] = f2bf(Wf3[i]); return; }
  i -= 8192;
  if (i < 12288){
    int g = i >> 6;
    float s = (g < 128) ? SGC : THC;
    wgt[413696 + i] = f2bf(Whh_n[i] * s); return;
  }
  i -= 12288;
  if (i < 1536){
    int t = i >> 7, rem = i & 127, cc = rem >> 3, j = rem & 7;
    float s = (t < 8) ? SGC : THC;
    int g = (t < 4) ? (t*16 + cc) : (t < 8) ? (64 + (t-4)*16 + cc) : (128 + (t-8)*16 + cc);
    float v = 0.f;
    if (j == 0) v = Wih_n[g*2]   * s;
    if (j == 1) v = Wih_n[g*2+1] * s;
    if (j == 2) v = ((t < 8) ? (bih_n[g] + bhh_n[g]) : bih_n[g]) * s;
    wgt[425984 + i] = f2bf(v); return;
  }
}

// ---------------- neighbor GRU (col-wave, h double-buffered) + pooling ----------------
// 2048 blocks x 256 threads; ONE batch per block.
// Wave w owns hidden cols [w*16,w*16+16); B-frags step-invariant in regs.
// h DOUBLE-BUFFERED (hb0/hb1) -> ONE barrier per step (was 2 in r12).
// LDS 20480 B: hb0 9216 | hb1 9216 | xpk/pool 2048.
__global__ __launch_bounds__(256, 4) void k_gru_n(
    const float* __restrict__ ttraj, const float* __restrict__ ntraj,
    const float* __restrict__ rang,  const float* __restrict__ nmask,
    const float* __restrict__ bhh_n,
    const unsigned short* __restrict__ wgt,
    unsigned short* __restrict__ sf)             // [16384][96] bf16
{
  __shared__ char smem[20480];
  const int tid = threadIdx.x;
  const int w = tid >> 6, u = (tid >> 4) & 3, c = tid & 15;
  const int b = blockIdx.x;
  const unsigned short* whhN_b = wgt + 413696;   // [192][64] prescaled
  const unsigned short* wxg    = wgt + 425984;   // [12][16][8]

  unsigned short* hb0 = (unsigned short*)smem;              // [64][72]
  unsigned short* hb1 = (unsigned short*)(smem + 9216);     // [64][72]
  unsigned* xpk = (unsigned*)(smem + 18432);                // [8][64] u32
  float* pool   = (float*)(smem + 18432);                   // alias (512 f32)

  // step-invariant B fragments -> registers
  short8 Bh[6], Bx[3];
#pragma unroll
  for (int k = 0; k < 3; ++k){           // 0=r, 1=z, 2=n
    int nt = k*4 + w;
    Bh[k*2+0] = *(const short8*)&whhN_b[(nt*16 + c)*64 + u*8];
    Bh[k*2+1] = *(const short8*)&whhN_b[(nt*16 + c)*64 + 32 + u*8];
    Bx[k]     = *(const short8*)&wxg[nt*128 + c*8];
  }
  const float bh_ = bhh_n[128 + w*16 + c] * THC;

  // stage trajectories packed bf16: xpk[step][seq]
  {
    float4 v = ((const float4*)(ntraj + (size_t)b * 1024))[tid];
    int n = tid >> 2, p = (tid & 3) * 2;
    xpk[p*64 + n]     = f2bf_pk(v.x, v.y);
    xpk[(p+1)*64 + n] = f2bf_pk(v.z, v.w);
  }
  __syncthreads();

  float hcur[4][4];
#pragma unroll
  for (int sg=0; sg<4; ++sg)
#pragma unroll
    for (int q=0; q<4; ++q) hcur[sg][q] = 0.0f;

  const f32x4 zz = {0.f,0.f,0.f,0.f};

#pragma unroll 1
  for (int st = 0; st < 8; ++st){
    // st writes wbuf; st reads buffer written at st-1
    unsigned short* wbuf = (st & 1) ? hb1 : hb0;
    unsigned short* rbuf = (st & 1) ? hb0 : hb1;

    short8 a0s[4], a1s[4];
    unsigned xv[4];
#pragma unroll
    for (int sg = 0; sg < 4; ++sg){
      xv[sg] = xpk[st*64 + sg*16 + c];
      if (st > 0){
        a0s[sg] = *(short8*)&rbuf[(sg*16 + c)*72 + u*8];
        a1s[sg] = *(short8*)&rbuf[(sg*16 + c)*72 + 32 + u*8];
      }
    }

#pragma unroll
    for (int sg = 0; sg < 4; ++sg){
      union { unsigned ui[4]; short8 s8; } a2u;
      a2u.ui[0] = (u == 0) ? xv[sg] : 0u;
      a2u.ui[1] = (u == 0) ? 0x3F80u : 0u;   // bf16(1.0) in halfword 2
      a2u.ui[2] = 0u; a2u.ui[3] = 0u;
      short8 a2 = a2u.s8;

      f32x4 aR = __builtin_amdgcn_mfma_f32_16x16x32_bf16(a2, Bx[0], zz, 0,0,0);
      f32x4 aZ = __builtin_amdgcn_mfma_f32_16x16x32_bf16(a2, Bx[1], zz, 0,0,0);
      f32x4 aX = __builtin_amdgcn_mfma_f32_16x16x32_bf16(a2, Bx[2], zz, 0,0,0);
      f32x4 aN = zz;
      if (st > 0){
        aR = __builtin_amdgcn_mfma_f32_16x16x32_bf16(a0s[sg], Bh[0], aR, 0,0,0);
        aR = __builtin_amdgcn_mfma_f32_16x16x32_bf16(a1s[sg], Bh[1], aR, 0,0,0);
        aZ = __builtin_amdgcn_mfma_f32_16x16x32_bf16(a0s[sg], Bh[2], aZ, 0,0,0);
        aZ = __builtin_amdgcn_mfma_f32_16x16x32_bf16(a1s[sg], Bh[3], aZ, 0,0,0);
        aN = __builtin_amdgcn_mfma_f32_16x16x32_bf16(a0s[sg], Bh[4], aN, 0,0,0);
        aN = __builtin_amdgcn_mfma_f32_16x16x32_bf16(a1s[sg], Bh[5], aN, 0,0,0);
      }
#pragma unroll
      for (int q = 0; q < 4; ++q){
        float r = __builtin_amdgcn_rcpf(1.0f + __builtin_amdgcn_exp2f(aR[q]));
        float z = __builtin_amdgcn_rcpf(1.0f + __builtin_amdgcn_exp2f(aZ[q]));
        float hn = aN[q] + bh_;
        float pn = __builtin_fmaf(r, hn, aX[q]);
        float E = __builtin_amdgcn_exp2f(pn);
        float n = __builtin_fmaf(-2.0f, __builtin_amdgcn_rcpf(E + 1.0f), 1.0f);
        float hnew = __builtin_fmaf(z, hcur[sg][q] - n, n);
        hcur[sg][q] = hnew;
        wbuf[(sg*16 + u*4 + q)*72 + w*16 + c] = (unsigned short)f2bf_cvt(hnew);
      }
    }
    __syncthreads();                     // single barrier per step
  }
  // final h (st=7) lives in hb1

  // ---- sector pooling ----
  if (tid < 64){
    int n = tid;
    const float* nb = ntraj + (size_t)b*1024 + n*16;
    float px = nb[14], py = nb[15];
    float vx = px - nb[12], vy = py - nb[13];
    float m   = nmask[(size_t)b*64 + n];
    float ang = rang[(size_t)b*64 + n];
    float tx = ttraj[(size_t)b*16 + 14], ty = ttraj[(size_t)b*16 + 15];
    float dx = px - tx, dy = py - ty;
    float dist = __builtin_amdgcn_sqrtf(dx*dx + dy*dy);
    int sid = (int)(ang / 0.78539816339744830962f);
    sid = sid < 0 ? 0 : (sid > 7 ? 7 : sid);
    bool valid = m > 0.0f;
    float wv = valid ? __builtin_amdgcn_exp2f(dist * -0.14426950408889634f) : 0.0f;
    pool[n]       = valid ? dist : 0.0f;
    pool[64 + n]  = valid ? vx   : 0.0f;
    pool[128 + n] = valid ? vy   : 0.0f;
    pool[192 + n] = wv;
    pool[256 + n] = valid ? (float)sid : -1.0f;
  }
  __syncthreads();
  if (tid < 8){
    int s = tid;
    float cnt=0.f, sd=0.f, sx=0.f, sy=0.f, sw=0.f;
#pragma unroll 4
    for (int n=0; n<64; ++n){
      if (pool[256+n] == (float)s){
        cnt += 1.f; sd += pool[n]; sx += pool[64+n]; sy += pool[128+n]; sw += pool[192+n];
      }
    }
    float inv = (cnt > 0.f) ? __builtin_amdgcn_rcpf(cnt) : 0.f;
    pool[320 + s] = cnt;
    pool[328 + s] = sd * inv;
    pool[336 + s] = sx * inv;
    pool[344 + s] = sy * inv;
    pool[352 + s] = __builtin_amdgcn_rcpf(sw + 1e-8f);
  }
  __syncthreads();
#pragma unroll
  for (int rep = 0; rep < 2; ++rep){
    int p = tid + rep*256;
    int s = p >> 6, h = p & 63;
    float fs = (float)s;
    float a = 0.f;
#pragma unroll 4
    for (int n = 0; n < 64; ++n){
      float wmv = (pool[256+n] == fs) ? pool[192+n] : 0.f;
      float nf  = bf2f(hb1[n*72 + h]);
      a += wmv * nf;
    }
    sf[((size_t)b*8 + s)*96 + 4 + h] = (unsigned short)f2bf_cvt(a * pool[352+s]);
  }
  if (tid < 32){
    int s = tid >> 2, cc = tid & 3;
    sf[((size_t)b*8 + s)*96 + cc] = (unsigned short)f2bf_cvt(pool[320 + cc*8 + s]);
  }
  if (tid < 224){
    int s = tid / 28, cc = 68 + tid % 28;
    sf[((size_t)b*8 + s)*96 + cc] = 0;
  }
}

// ---------------- target GRU: 128 blocks x 256 thr (4 waves) ----------------
// Output tfeat [2048][128] (compact; head reads it directly).
__global__ __launch_bounds__(256) void k_gru_t(
    const float* __restrict__ ttraj,
    const float* __restrict__ Wih_t, const float* __restrict__ bih_t, const float* __restrict__ bhh_t,
    const unsigned short* __restrict__ wgt,      // whhT_b [384][128] @0
    unsigned short* __restrict__ tfeat)          // [2048][128] bf16
{
  __shared__ char smem[9728];
  const int tid = threadIdx.x, w = tid >> 6, u = (tid >> 4) & 3, c = tid & 15;
  unsigned short* hb0 = (unsigned short*)smem;             // [16][136]
  unsigned short* hb1 = (unsigned short*)(smem + 4352);    // [16][136]
  float* xs = (float*)(smem + 8704);                       // [16][16]

  xs[tid] = ttraj[(size_t)blockIdx.x*256 + tid];

  int ntg[6];
  ntg[0] = 2*w; ntg[1] = 2*w+1;
  ntg[2] = 8+2*w; ntg[3] = 9+2*w;
  ntg[4] = 16+2*w; ntg[5] = 17+2*w;

  short8 Bf[6][4];
#pragma unroll
  for (int lt2 = 0; lt2 < 6; ++lt2){
    const unsigned short* wp = wgt + (ntg[lt2]*16 + c)*128 + u*8;
#pragma unroll
    for (int kk = 0; kk < 4; ++kk)
      Bf[lt2][kk] = *(const short8*)(wp + kk*32);
  }

  float Wr0[2],Wr1[2],BR[2],Wz0[2],Wz1[2],BZ[2],Wn0[2],Wn1[2],BI[2],BH[2];
#pragma unroll
  for (int gt = 0; gt < 2; ++gt){
    int g = w*32 + gt*16 + c;
    Wr0[gt]=Wih_t[g*2]*SGC;        Wr1[gt]=Wih_t[g*2+1]*SGC;        BR[gt]=(bih_t[g]+bhh_t[g])*SGC;
    Wz0[gt]=Wih_t[(128+g)*2]*SGC;  Wz1[gt]=Wih_t[(128+g)*2+1]*SGC;  BZ[gt]=(bih_t[128+g]+bhh_t[128+g])*SGC;
    Wn0[gt]=Wih_t[(256+g)*2]*THC;  Wn1[gt]=Wih_t[(256+g)*2+1]*THC;  BI[gt]=bih_t[256+g]*THC; BH[gt]=bhh_t[256+g]*THC;
  }
  float hcur[2][4];
#pragma unroll
  for (int gt=0; gt<2; ++gt)
#pragma unroll
    for (int q=0; q<4; ++q) hcur[gt][q] = 0.0f;
  __syncthreads();

#pragma unroll 1
  for (int st = 0; st < 8; ++st){
    unsigned short* rbuf = (st & 1) ? hb0 : hb1;
    unsigned short* wbuf = (st & 1) ? hb1 : hb0;
    f32x4 acc[6];
    if (st > 0){
      short8 a0 = *(short8*)&rbuf[c*136 + u*8];
      short8 a1 = *(short8*)&rbuf[c*136 + 32 + u*8];
      short8 a2 = *(short8*)&rbuf[c*136 + 64 + u*8];
      short8 a3 = *(short8*)&rbuf[c*136 + 96 + u*8];
#pragma unroll
      for (int lt2 = 0; lt2 < 6; ++lt2){
        f32x4 t = {0.f,0.f,0.f,0.f};
        t = __builtin_amdgcn_mfma_f32_16x16x32_bf16(a0, Bf[lt2][0], t, 0,0,0);
        t = __builtin_amdgcn_mfma_f32_16x16x32_bf16(a1, Bf[lt2][1], t, 0,0,0);
        t = __builtin_amdgcn_mfma_f32_16x16x32_bf16(a2, Bf[lt2][2], t, 0,0,0);
        acc[lt2] = __builtin_amdgcn_mfma_f32_16x16x32_bf16(a3, Bf[lt2][3], t, 0,0,0);
      }
    } else {
#pragma unroll
      for (int lt2 = 0; lt2 < 6; ++lt2) acc[lt2] = (f32x4){0.f,0.f,0.f,0.f};
    }
#pragma unroll
    for (int gt = 0; gt < 2; ++gt){
#pragma unroll
      for (int q = 0; q < 4; ++q){
        int sq = u*4 + q;
        float x0 = xs[sq*16 + st*2], x1 = xs[sq*16 + st*2 + 1];
        float rp = __builtin_fmaf(Wr0[gt], x0, __builtin_fmaf(Wr1[gt], x1, acc[gt][q] + BR[gt]));
        float zp = __builtin_fmaf(Wz0[gt], x0, __builtin_fmaf(Wz1[gt], x1, acc[2+gt][q] + BZ[gt]));
        float r = __builtin_amdgcn_rcpf(1.0f + __builtin_amdgcn_exp2f(rp));
        float z = __builtin_amdgcn_rcpf(1.0f + __builtin_amdgcn_exp2f(zp));
        float hnv = acc[4+gt][q] + BH[gt];
        float pn = __builtin_fmaf(Wn0[gt], x0, __builtin_fmaf(Wn1[gt], x1, __builtin_fmaf(r, hnv, BI[gt])));
        float E = __builtin_amdgcn_exp2f(pn);
        float n = __builtin_fmaf(-2.0f, __builtin_amdgcn_rcpf(E + 1.0f), 1.0f);
        float hnew = __builtin_fmaf(z, hcur[gt][q] - n, n);
        hcur[gt][q] = hnew;
        if (st < 7){
          wbuf[sq*136 + w*32 + gt*16 + c] = (unsigned short)f2bf_cvt(hnew);
        } else {
          int row = blockIdx.x*16 + sq;
          tfeat[(size_t)row*128 + w*32 + gt*16 + c] = (unsigned short)f2bf_cvt(hnew);
        }
      }
    }
    if (st < 7) __syncthreads();
  }
}

// ---------------- fused MLP1/2 + head: 128 blocks x 256 thr ----------------
// Block = 16 batches. Phase 1: MLP1(96->128)+MLP2(128->128) for the block's
// 128 sector-rows -> encl in LDS (enc never touches HBM). Phase 2: head
// f1(1152->256)->f2(256->128)->f3(128->64)->LayerNorm -> out.
__global__ __launch_bounds__(256) void k_mlp_head(
    const unsigned short* __restrict__ sf,     // [16384][96]
    const unsigned short* __restrict__ tfeat,  // [2048][128]
    const unsigned short* __restrict__ wgt,
    const float* __restrict__ b1,  const float* __restrict__ b2,
    const float* __restrict__ bf1, const float* __restrict__ bf2,
    const float* __restrict__ bf3,
    const float* __restrict__ lng, const float* __restrict__ lnb,
    float* __restrict__ out)
{
  __shared__ char smem[53504];
  const int tid = threadIdx.x, w = tid >> 6, u = (tid >> 4) & 3, c = tid & 15;
  unsigned short* encl = (unsigned short*)smem;              // [16][1024]
  char* scr = smem + 32768;                                  // 17408 B scratch
  unsigned short* h1l = (unsigned short*)(scr + w*4352);     // [16][136]/wave
  unsigned short* f1b = (unsigned short*)scr;                // [16][264] (head)
  unsigned short* f2b = (unsigned short*)(scr + 8448);       // [16][136] (head)
  float* bf1s = (float*)(smem + 50176);
  float* bf2s = (float*)(smem + 51200);
  float* bf3s = (float*)(smem + 51712);
  float* lngs = (float*)(smem + 51968);
  float* lnbs = (float*)(smem + 52224);
  float* b1s  = (float*)(smem + 52480);
  float* b2s  = (float*)(smem + 52992);
  const unsigned short* w1b  = wgt + 49152;
  const unsigned short* w2b  = wgt + 61440;
  const unsigned short* wf1b = wgt + 77824;
  const unsigned short* wf2b = wgt + 372736;
  const unsigned short* wf3b = wgt + 405504;

  bf1s[tid] = bf1[tid];
  if (tid < 128){ bf2s[tid] = bf2[tid]; b1s[tid] = b1[tid]; b2s[tid] = b2[tid]; }
  if (tid < 64){ bf3s[tid] = bf3[tid]; lngs[tid] = lng[tid]; lnbs[tid] = lnb[tid]; }
  __syncthreads();

  const f32x4 zz = {0.f,0.f,0.f,0.f};

  // ---- phase 1: MLP over this block's 128 sector rows; wave w: tiles 2w, 2w+1 ----
#pragma unroll
  for (int ti = 0; ti < 2; ++ti){
    int t = 2*w + ti;
    int rowb_s = blockIdx.x*128 + t*16;
    f32x4 acc[8];
#pragma unroll
    for (int nt=0; nt<8; ++nt) acc[nt] = zz;
#pragma unroll
    for (int kc=0; kc<3; ++kc){
      short8 a = *(const short8*)&sf[(size_t)(rowb_s + c)*96 + kc*32 + u*8];
#pragma unroll
      for (int nt=0; nt<8; ++nt){
        short8 bb = *(const short8*)&w1b[(nt*16+c)*96 + kc*32 + u*8];
        acc[nt] = __builtin_amdgcn_mfma_f32_16x16x32_bf16(a, bb, acc[nt], 0,0,0);
      }
    }
#pragma unroll
    for (int nt=0; nt<8; ++nt){
      float bias = b1s[nt*16+c];
#pragma unroll
      for (int q=0; q<4; ++q){
        float v = acc[nt][q] + bias; v = v > 0.f ? v : 0.f;
        h1l[(u*4+q)*136 + nt*16 + c] = (unsigned short)f2bf_cvt(v);
      }
    }
    f32x4 acc2[8];
#pragma unroll
    for (int nt=0; nt<8; ++nt) acc2[nt] = zz;
#pragma unroll
    for (int kc=0; kc<4; ++kc){
      short8 a = *(short8*)&h1l[c*136 + kc*32 + u*8];
#pragma unroll
      for (int nt=0; nt<8; ++nt){
        short8 bb = *(const short8*)&w2b[(nt*16+c)*128 + kc*32 + u*8];
        acc2[nt] = __builtin_amdgcn_mfma_f32_16x16x32_bf16(a, bb, acc2[nt], 0,0,0);
      }
    }
#pragma unroll
    for (int nt=0; nt<8; ++nt){
      float bias = b2s[nt*16+c];
#pragma unroll
      for (int q=0; q<4; ++q){
        float v = acc2[nt][q] + bias; v = v > 0.f ? v : 0.f;
        int rloc = t*16 + u*4 + q;          // local sector row 0..127
        int bl = rloc >> 3, s = rloc & 7;
        encl[bl*1024 + s*128 + nt*16 + c] = (unsigned short)f2bf_cvt(v);
      }
    }
  }
  __syncthreads();   // encl complete; scratch now free for f1b/f2b

  // ---- phase 2: head ----
  const int rowb = blockIdx.x * 16;

  f32x4 acc[4];
#pragma unroll
  for (int i=0; i<4; ++i) acc[i] = zz;
#pragma unroll
  for (int kc=0; kc<4; ++kc){          // target-feature part from tfeat
    short8 a = *(const short8*)&tfeat[(size_t)(rowb + c)*128 + kc*32 + u*8];
#pragma unroll
    for (int i=0; i<4; ++i){
      int nt = w*4 + i;
      short8 bb = *(const short8*)&wf1b[(size_t)(nt*16+c)*1152 + kc*32 + u*8];
      acc[i] = __builtin_amdgcn_mfma_f32_16x16x32_bf16(a, bb, acc[i], 0,0,0);
    }
  }
#pragma unroll 4
  for (int kc=4; kc<36; ++kc){         // enc part from LDS
    short8 a = *(const short8*)&encl[c*1024 + (kc-4)*32 + u*8];
#pragma unroll
    for (int i=0; i<4; ++i){
      int nt = w*4 + i;
      short8 bb = *(const short8*)&wf1b[(size_t)(nt*16+c)*1152 + kc*32 + u*8];
      acc[i] = __builtin_amdgcn_mfma_f32_16x16x32_bf16(a, bb, acc[i], 0,0,0);
    }
  }
#pragma unroll
  for (int i=0; i<4; ++i){
    int nt = w*4 + i;
    float bias = bf1s[nt*16+c];
#pragma unroll
    for (int q=0; q<4; ++q){
      float v = acc[i][q] + bias; v = v > 0.f ? v : 0.f;
      f1b[(u*4+q)*264 + nt*16 + c] = (unsigned short)f2bf_cvt(v);
    }
  }
  __syncthreads();

  f32x4 acc2[2];
#pragma unroll
  for (int i=0; i<2; ++i) acc2[i] = zz;
#pragma unroll
  for (int kc=0; kc<8; ++kc){
    short8 a = *(short8*)&f1b[c*264 + kc*32 + u*8];
#pragma unroll
    for (int i=0; i<2; ++i){
      int nt = w*2 + i;
      short8 bb = *(const short8*)&wf2b[(nt*16+c)*256 + kc*32 + u*8];
      acc2[i] = __builtin_amdgcn_mfma_f32_16x16x32_bf16(a, bb, acc2[i], 0,0,0);
    }
  }
#pragma unroll
  for (int i=0; i<2; ++i){
    int nt = w*2 + i;
    float bias = bf2s[nt*16+c];
#pragma unroll
    for (int q=0; q<4; ++q){
      float v = acc2[i][q] + bias; v = v > 0.f ? v : 0.f;
      f2b[(u*4+q)*136 + nt*16 + c] = (unsigned short)f2bf_cvt(v);
    }
  }
  __syncthreads();

  f32x4 acc3[4];
#pragma unroll
  for (int nt=0; nt<4; ++nt) acc3[nt] = zz;
#pragma unroll
  for (int kc=0; kc<4; ++kc){
    short8 a = *(short8*)&f2b[c*136 + kc*32 + u*8];
#pragma unroll
    for (int nt=0; nt<4; ++nt){
      short8 bb = *(const short8*)&wf3b[(nt*16+c)*128 + kc*32 + u*8];
      acc3[nt] = __builtin_amdgcn_mfma_f32_16x16x32_bf16(a, bb, acc3[nt], 0,0,0);
    }
  }
  if (w == 0){
    float v[4][4];
#pragma unroll
    for (int nt=0; nt<4; ++nt){
      float bias = bf3s[nt*16+c];
#pragma unroll
      for (int q=0; q<4; ++q){
        float t = acc3[nt][q] + bias; v[nt][q] = t > 0.f ? t : 0.f;
      }
    }
#pragma unroll
    for (int q=0; q<4; ++q){
      float p = v[0][q] + v[1][q] + v[2][q] + v[3][q];
      p += __shfl_xor(p, 1); p += __shfl_xor(p, 2); p += __shfl_xor(p, 4); p += __shfl_xor(p, 8);
      float mu = p * 0.015625f;
      float d0 = v[0][q]-mu, d1 = v[1][q]-mu, d2 = v[2][q]-mu, d3 = v[3][q]-mu;
      float p2 = d0*d0 + d1*d1 + d2*d2 + d3*d3;
      p2 += __shfl_xor(p2, 1); p2 += __shfl_xor(p2, 2); p2 += __shfl_xor(p2, 4); p2 += __shfl_xor(p2, 8);
      float rstd = __builtin_amdgcn_rsqf(p2 * 0.015625f + 1e-5f);
      int row = rowb + u*4 + q;
#pragma unroll
      for (int nt=0; nt<4; ++nt){
        int col = nt*16 + c;
        out[(size_t)row*64 + col] = (v[nt][q] - mu) * rstd * lngs[col] + lnbs[col];
      }
    }
  }
}

extern "C" void kernel_launch(void* const* d_in, const int* in_sizes, int n_in,
                              void* d_out, int out_size, void* d_ws, size_t ws_size,
                              hipStream_t stream)
{
  const float* ttraj = (const float*)d_in[0];
  const float* ntraj = (const float*)d_in[1];
  const float* rang  = (const float*)d_in[2];
  const float* nmask = (const float*)d_in[3];
  const float* Wih_t = (const float*)d_in[4];
  const float* Whh_t = (const float*)d_in[5];
  const float* bih_t = (const float*)d_in[6];
  const float* bhh_t = (const float*)d_in[7];
  const float* Wih_n = (const float*)d_in[8];
  const float* Whh_n = (const float*)d_in[9];
  const float* bih_n = (const float*)d_in[10];
  const float* bhh_n = (const float*)d_in[11];
  const float* W1  = (const float*)d_in[12];
  const float* b1  = (const float*)d_in[13];
  const float* W2  = (const float*)d_in[14];
  const float* b2  = (const float*)d_in[15];
  const float* Wf1 = (const float*)d_in[16];
  const float* bf1 = (const float*)d_in[17];
  const float* Wf2 = (const float*)d_in[18];
  const float* bf2 = (const float*)d_in[19];
  const float* Wf3 = (const float*)d_in[20];
  const float* bf3 = (const float*)d_in[21];
  const float* lng = (const float*)d_in[22];
  const float* lnb = (const float*)d_in[23];

  char* ws = (char*)d_ws;
  unsigned short* tfeat = (unsigned short*)ws;                     // [2048][128] bf16
  unsigned short* sf    = (unsigned short*)(ws + 5242880);         // [16384][96] bf16
  unsigned short* wgt   = (unsigned short*)(ws + 8388608);         // bf16 weights

  hipLaunchKernelGGL(k_prep, dim3(1670), dim3(256), 0, stream,
                     Whh_t, W1, W2, Wf1, Wf2, Wf3, Whh_n, Wih_n, bih_n, bhh_n, wgt);
  hipLaunchKernelGGL(k_gru_n, dim3(2048), dim3(256), 0, stream,
                     ttraj, ntraj, rang, nmask, bhh_n, wgt, sf);
  hipLaunchKernelGGL(k_gru_t, dim3(128), dim3(256), 0, stream,
                     ttraj, Wih_t, bih_t, bhh_t, wgt, tfeat);
  hipLaunchKernelGGL(k_mlp_head, dim3(128), dim3(256), 0, stream,
                     sf, tfeat, wgt, b1, b2, bf1, bf2, bf3, lng, lnb, (float*)d_out);
}

// Round 15
// 137.417 us; speedup vs baseline: 1.2262x; 1.0636x over previous
//
#include <hip/hip_runtime.h>

typedef __attribute__((ext_vector_type(8))) short short8;
typedef __attribute__((ext_vector_type(4))) float f32x4;

#define SGC (-1.44269504088896341f)   /* -log2(e): sigmoid prescale */
#define THC ( 2.88539008177792681f)   /* 2*log2(e): tanh prescale   */

__device__ __forceinline__ unsigned short f2bf(float f){
  unsigned u = __float_as_uint(f);
  return (unsigned short)((u + 0x7fffu + ((u >> 16) & 1u)) >> 16);
}
__device__ __forceinline__ float bf2f(unsigned short b){
  return __uint_as_float(((unsigned)b) << 16);
}
__device__ __forceinline__ unsigned f2bf_cvt(float f){
  unsigned r;
  asm("v_cvt_pk_bf16_f32 %0, %1, %1" : "=v"(r) : "v"(f));
  return r;
}
__device__ __forceinline__ unsigned f2bf_pk(float lo, float hi){
  unsigned r;
  asm("v_cvt_pk_bf16_f32 %0, %1, %2" : "=v"(r) : "v"(lo), "v"(hi));
  return r;
}

// wgt layout (u16 elems) — consumed by gru_t / mlp12 / head only:
//   whhT_b [384*128]  @0        (PRESCALED: rows<256 *SGC, rows>=256 *THC)
//   W1b    [128*96]   @49152    (96 = 68 padded, zeros)
//   W2b    [128*128]  @61440
//   Wf1b   [256*1152] @77824
//   Wf2b   [128*256]  @372736
//   Wf3b   [64*128]   @405504   (total 413696 -> 1616 prep blocks)

// ---------------- merged: prep (blocks 0..1615) | neighbor GRU (1616..3663) ----------------
// gru_n: col-wave, self-converting weights (r13-proven, no wgt dependency),
// h double-buffered (1 barrier/step), LDS 20480 B.
__global__ __launch_bounds__(256, 4) void k_gn(
    const float* __restrict__ ttraj, const float* __restrict__ ntraj,
    const float* __restrict__ rang,  const float* __restrict__ nmask,
    const float* __restrict__ Wih_n, const float* __restrict__ bih_n,
    const float* __restrict__ bhh_n, const float* __restrict__ Whh_n,
    const float* __restrict__ Whh_t, const float* __restrict__ W1,
    const float* __restrict__ W2,    const float* __restrict__ Wf1,
    const float* __restrict__ Wf2,   const float* __restrict__ Wf3,
    unsigned short* __restrict__ wgt,
    unsigned short* __restrict__ sf)             // [16384][96] bf16
{
  __shared__ char smem[20480];
  const int tid = threadIdx.x;

  if (blockIdx.x < 1616){
    // ================= prep: fp32 -> bf16 weights =================
    int i = blockIdx.x * 256 + tid;
    if (i < 49152){
      int g = i >> 7;
      float s = (g < 256) ? SGC : THC;
      wgt[i] = f2bf(Whh_t[i] * s); return;
    }
    i -= 49152;
    if (i < 12288){ int r = i / 96, cc = i % 96;
      wgt[49152 + i] = (cc < 68) ? f2bf(W1[r*68 + cc]) : (unsigned short)0; return; }
    i -= 12288;
    if (i < 16384){ wgt[61440 + i] = f2bf(W2[i]); return; }
    i -= 16384;
    if (i < 294912){ wgt[77824 + i] = f2bf(Wf1[i]); return; }
    i -= 294912;
    if (i < 32768){ wgt[372736 + i] = f2bf(Wf2[i]); return; }
    i -= 32768;
    if (i < 8192){ wgt[405504 + i] = f2bf(Wf3[i]); return; }
    return;
  }

  // ================= neighbor GRU (col-wave) + pooling =================
  const int b = blockIdx.x - 1616;
  const int w = tid >> 6, u = (tid >> 4) & 3, c = tid & 15;

  unsigned short* hb0 = (unsigned short*)smem;              // [64][72]
  unsigned short* hb1 = (unsigned short*)(smem + 9216);     // [64][72]
  unsigned* xpk = (unsigned*)(smem + 18432);                // [8][64] u32
  float* pool   = (float*)(smem + 18432);                   // alias (512 f32)

  // self-convert step-invariant B fragments (prescaled) from fp32 [r13-proven]
  short8 Bh[6], Bx[3];
#pragma unroll
  for (int k = 0; k < 3; ++k){           // 0=r, 1=z, 2=n
    float s = (k < 2) ? SGC : THC;
    const float* src = Whh_n + ((size_t)((k*4 + w)*16 + c))*64;
#pragma unroll
    for (int h = 0; h < 2; ++h){
      const float* p = src + h*32 + u*8;
      union { unsigned ui[4]; short8 s8; } t;
#pragma unroll
      for (int j = 0; j < 4; ++j) t.ui[j] = f2bf_pk(p[2*j]*s, p[2*j+1]*s);
      Bh[k*2+h] = t.s8;
    }
    int g = k*64 + w*16 + c;
    float bsum = ((k < 2) ? (bih_n[g] + bhh_n[g]) : bih_n[g]);
    union { unsigned ui[4]; short8 s8; } tx;
    tx.ui[0] = f2bf_pk(Wih_n[g*2]*s, Wih_n[g*2+1]*s);
    tx.ui[1] = f2bf_pk(bsum*s, 0.f);
    tx.ui[2] = 0u; tx.ui[3] = 0u;
    Bx[k] = tx.s8;
  }
  const float bh_ = bhh_n[128 + w*16 + c] * THC;

  // stage trajectories packed bf16: xpk[step][seq]
  {
    float4 v = ((const float4*)(ntraj + (size_t)b * 1024))[tid];
    int n = tid >> 2, p = (tid & 3) * 2;
    xpk[p*64 + n]     = f2bf_pk(v.x, v.y);
    xpk[(p+1)*64 + n] = f2bf_pk(v.z, v.w);
  }
  __syncthreads();

  float hcur[4][4];
#pragma unroll
  for (int sg=0; sg<4; ++sg)
#pragma unroll
    for (int q=0; q<4; ++q) hcur[sg][q] = 0.0f;

  const f32x4 zz = {0.f,0.f,0.f,0.f};

#pragma unroll 1
  for (int st = 0; st < 8; ++st){
    unsigned short* wbuf = (st & 1) ? hb1 : hb0;
    unsigned short* rbuf = (st & 1) ? hb0 : hb1;

    short8 a0s[4], a1s[4];
    unsigned xv[4];
#pragma unroll
    for (int sg = 0; sg < 4; ++sg){
      xv[sg] = xpk[st*64 + sg*16 + c];
      if (st > 0){
        a0s[sg] = *(short8*)&rbuf[(sg*16 + c)*72 + u*8];
        a1s[sg] = *(short8*)&rbuf[(sg*16 + c)*72 + 32 + u*8];
      }
    }

#pragma unroll
    for (int sg = 0; sg < 4; ++sg){
      union { unsigned ui[4]; short8 s8; } a2u;
      a2u.ui[0] = (u == 0) ? xv[sg] : 0u;
      a2u.ui[1] = (u == 0) ? 0x3F80u : 0u;   // bf16(1.0) in halfword 2
      a2u.ui[2] = 0u; a2u.ui[3] = 0u;
      short8 a2 = a2u.s8;

      f32x4 aR = __builtin_amdgcn_mfma_f32_16x16x32_bf16(a2, Bx[0], zz, 0,0,0);
      f32x4 aZ = __builtin_amdgcn_mfma_f32_16x16x32_bf16(a2, Bx[1], zz, 0,0,0);
      f32x4 aX = __builtin_amdgcn_mfma_f32_16x16x32_bf16(a2, Bx[2], zz, 0,0,0);
      f32x4 aN = zz;
      if (st > 0){
        aR = __builtin_amdgcn_mfma_f32_16x16x32_bf16(a0s[sg], Bh[0], aR, 0,0,0);
        aR = __builtin_amdgcn_mfma_f32_16x16x32_bf16(a1s[sg], Bh[1], aR, 0,0,0);
        aZ = __builtin_amdgcn_mfma_f32_16x16x32_bf16(a0s[sg], Bh[2], aZ, 0,0,0);
        aZ = __builtin_amdgcn_mfma_f32_16x16x32_bf16(a1s[sg], Bh[3], aZ, 0,0,0);
        aN = __builtin_amdgcn_mfma_f32_16x16x32_bf16(a0s[sg], Bh[4], aN, 0,0,0);
        aN = __builtin_amdgcn_mfma_f32_16x16x32_bf16(a1s[sg], Bh[5], aN, 0,0,0);
      }
#pragma unroll
      for (int q = 0; q < 4; ++q){
        float r = __builtin_amdgcn_rcpf(1.0f + __builtin_amdgcn_exp2f(aR[q]));
        float z = __builtin_amdgcn_rcpf(1.0f + __builtin_amdgcn_exp2f(aZ[q]));
        float hn = aN[q] + bh_;
        float pn = __builtin_fmaf(r, hn, aX[q]);
        float E = __builtin_amdgcn_exp2f(pn);
        float n = __builtin_fmaf(-2.0f, __builtin_amdgcn_rcpf(E + 1.0f), 1.0f);
        float hnew = __builtin_fmaf(z, hcur[sg][q] - n, n);
        hcur[sg][q] = hnew;
        wbuf[(sg*16 + u*4 + q)*72 + w*16 + c] = (unsigned short)f2bf_cvt(hnew);
      }
    }
    __syncthreads();
  }
  // final h (st=7) lives in hb1

  // ---- sector pooling ----
  if (tid < 64){
    int n = tid;
    const float* nb = ntraj + (size_t)b*1024 + n*16;
    float px = nb[14], py = nb[15];
    float vx = px - nb[12], vy = py - nb[13];
    float m   = nmask[(size_t)b*64 + n];
    float ang = rang[(size_t)b*64 + n];
    float tx = ttraj[(size_t)b*16 + 14], ty = ttraj[(size_t)b*16 + 15];
    float dx = px - tx, dy = py - ty;
    float dist = __builtin_amdgcn_sqrtf(dx*dx + dy*dy);
    int sid = (int)(ang / 0.78539816339744830962f);
    sid = sid < 0 ? 0 : (sid > 7 ? 7 : sid);
    bool valid = m > 0.0f;
    float wv = valid ? __builtin_amdgcn_exp2f(dist * -0.14426950408889634f) : 0.0f;
    pool[n]       = valid ? dist : 0.0f;
    pool[64 + n]  = valid ? vx   : 0.0f;
    pool[128 + n] = valid ? vy   : 0.0f;
    pool[192 + n] = wv;
    pool[256 + n] = valid ? (float)sid : -1.0f;
  }
  __syncthreads();
  if (tid < 8){
    int s = tid;
    float cnt=0.f, sd=0.f, sx=0.f, sy=0.f, sw=0.f;
#pragma unroll 4
    for (int n=0; n<64; ++n){
      if (pool[256+n] == (float)s){
        cnt += 1.f; sd += pool[n]; sx += pool[64+n]; sy += pool[128+n]; sw += pool[192+n];
      }
    }
    float inv = (cnt > 0.f) ? __builtin_amdgcn_rcpf(cnt) : 0.f;
    pool[320 + s] = cnt;
    pool[328 + s] = sd * inv;
    pool[336 + s] = sx * inv;
    pool[344 + s] = sy * inv;
    pool[352 + s] = __builtin_amdgcn_rcpf(sw + 1e-8f);
  }
  __syncthreads();
#pragma unroll
  for (int rep = 0; rep < 2; ++rep){
    int p = tid + rep*256;
    int s = p >> 6, h = p & 63;
    float fs = (float)s;
    float a = 0.f;
#pragma unroll 4
    for (int n = 0; n < 64; ++n){
      float wmv = (pool[256+n] == fs) ? pool[192+n] : 0.f;
      float nf  = bf2f(hb1[n*72 + h]);
      a += wmv * nf;
    }
    sf[((size_t)b*8 + s)*96 + 4 + h] = (unsigned short)f2bf_cvt(a * pool[352+s]);
  }
  if (tid < 32){
    int s = tid >> 2, cc = tid & 3;
    sf[((size_t)b*8 + s)*96 + cc] = (unsigned short)f2bf_cvt(pool[320 + cc*8 + s]);
  }
  if (tid < 224){
    int s = tid / 28, cc = 68 + tid % 28;
    sf[((size_t)b*8 + s)*96 + cc] = 0;
  }
}

// ---------------- target GRU: 128 blocks x 256 thr (4 waves) ----------------
__global__ __launch_bounds__(256) void k_gru_t(
    const float* __restrict__ ttraj,
    const float* __restrict__ Wih_t, const float* __restrict__ bih_t, const float* __restrict__ bhh_t,
    const unsigned short* __restrict__ wgt,      // whhT_b [384][128] @0
    unsigned short* __restrict__ combined)       // [2048][1152] bf16
{
  __shared__ char smem[9728];
  const int tid = threadIdx.x, w = tid >> 6, u = (tid >> 4) & 3, c = tid & 15;
  unsigned short* hb0 = (unsigned short*)smem;             // [16][136]
  unsigned short* hb1 = (unsigned short*)(smem + 4352);    // [16][136]
  float* xs = (float*)(smem + 8704);                       // [16][16]

  xs[tid] = ttraj[(size_t)blockIdx.x*256 + tid];

  int ntg[6];
  ntg[0] = 2*w; ntg[1] = 2*w+1;
  ntg[2] = 8+2*w; ntg[3] = 9+2*w;
  ntg[4] = 16+2*w; ntg[5] = 17+2*w;

  short8 Bf[6][4];
#pragma unroll
  for (int lt2 = 0; lt2 < 6; ++lt2){
    const unsigned short* wp = wgt + (ntg[lt2]*16 + c)*128 + u*8;
#pragma unroll
    for (int kk = 0; kk < 4; ++kk)
      Bf[lt2][kk] = *(const short8*)(wp + kk*32);
  }

  float Wr0[2],Wr1[2],BR[2],Wz0[2],Wz1[2],BZ[2],Wn0[2],Wn1[2],BI[2],BH[2];
#pragma unroll
  for (int gt = 0; gt < 2; ++gt){
    int g = w*32 + gt*16 + c;
    Wr0[gt]=Wih_t[g*2]*SGC;        Wr1[gt]=Wih_t[g*2+1]*SGC;        BR[gt]=(bih_t[g]+bhh_t[g])*SGC;
    Wz0[gt]=Wih_t[(128+g)*2]*SGC;  Wz1[gt]=Wih_t[(128+g)*2+1]*SGC;  BZ[gt]=(bih_t[128+g]+bhh_t[128+g])*SGC;
    Wn0[gt]=Wih_t[(256+g)*2]*THC;  Wn1[gt]=Wih_t[(256+g)*2+1]*THC;  BI[gt]=bih_t[256+g]*THC; BH[gt]=bhh_t[256+g]*THC;
  }
  float hcur[2][4];
#pragma unroll
  for (int gt=0; gt<2; ++gt)
#pragma unroll
    for (int q=0; q<4; ++q) hcur[gt][q] = 0.0f;
  __syncthreads();

#pragma unroll 1
  for (int st = 0; st < 8; ++st){
    unsigned short* rbuf = (st & 1) ? hb0 : hb1;
    unsigned short* wbuf = (st & 1) ? hb1 : hb0;
    f32x4 acc[6];
    if (st > 0){
      short8 a0 = *(short8*)&rbuf[c*136 + u*8];
      short8 a1 = *(short8*)&rbuf[c*136 + 32 + u*8];
      short8 a2 = *(short8*)&rbuf[c*136 + 64 + u*8];
      short8 a3 = *(short8*)&rbuf[c*136 + 96 + u*8];
#pragma unroll
      for (int lt2 = 0; lt2 < 6; ++lt2){
        f32x4 t = {0.f,0.f,0.f,0.f};
        t = __builtin_amdgcn_mfma_f32_16x16x32_bf16(a0, Bf[lt2][0], t, 0,0,0);
        t = __builtin_amdgcn_mfma_f32_16x16x32_bf16(a1, Bf[lt2][1], t, 0,0,0);
        t = __builtin_amdgcn_mfma_f32_16x16x32_bf16(a2, Bf[lt2][2], t, 0,0,0);
        acc[lt2] = __builtin_amdgcn_mfma_f32_16x16x32_bf16(a3, Bf[lt2][3], t, 0,0,0);
      }
    } else {
#pragma unroll
      for (int lt2 = 0; lt2 < 6; ++lt2) acc[lt2] = (f32x4){0.f,0.f,0.f,0.f};
    }
#pragma unroll
    for (int gt = 0; gt < 2; ++gt){
#pragma unroll
      for (int q = 0; q < 4; ++q){
        int sq = u*4 + q;
        float x0 = xs[sq*16 + st*2], x1 = xs[sq*16 + st*2 + 1];
        float rp = __builtin_fmaf(Wr0[gt], x0, __builtin_fmaf(Wr1[gt], x1, acc[gt][q] + BR[gt]));
        float zp = __builtin_fmaf(Wz0[gt], x0, __builtin_fmaf(Wz1[gt], x1, acc[2+gt][q] + BZ[gt]));
        float r = __builtin_amdgcn_rcpf(1.0f + __builtin_amdgcn_exp2f(rp));
        float z = __builtin_amdgcn_rcpf(1.0f + __builtin_amdgcn_exp2f(zp));
        float hnv = acc[4+gt][q] + BH[gt];
        float pn = __builtin_fmaf(Wn0[gt], x0, __builtin_fmaf(Wn1[gt], x1, __builtin_fmaf(r, hnv, BI[gt])));
        float E = __builtin_amdgcn_exp2f(pn);
        float n = __builtin_fmaf(-2.0f, __builtin_amdgcn_rcpf(E + 1.0f), 1.0f);
        float hnew = __builtin_fmaf(z, hcur[gt][q] - n, n);
        hcur[gt][q] = hnew;
        if (st < 7){
          wbuf[sq*136 + w*32 + gt*16 + c] = (unsigned short)f2bf_cvt(hnew);
        } else {
          int row = blockIdx.x*16 + sq;
          combined[(size_t)row*1152 + w*32 + gt*16 + c] = (unsigned short)f2bf_cvt(hnew);
        }
      }
    }
    if (st < 7) __syncthreads();
  }
}

// ---------------- MLP1/MLP2 over (b,s) rows: sf -> enc part of combined ----------------
__global__ __launch_bounds__(256) void k_mlp12(
    const unsigned short* __restrict__ sf,    // [16384][96]
    const unsigned short* __restrict__ wgt,
    const float* __restrict__ b1, const float* __restrict__ b2,
    unsigned short* __restrict__ combined)
{
  __shared__ char smem[18432];
  unsigned short* hb = (unsigned short*)smem + (threadIdx.x >> 6) * 2176;  // [16][136]/wave
  float* b1s = (float*)(smem + 17408);
  float* b2s = b1s + 128;
  const unsigned short* w1b = wgt + 49152;
  const unsigned short* w2b = wgt + 61440;
  const int tid = threadIdx.x, w = tid >> 6, u = (tid >> 4) & 3, c = tid & 15;
  if (tid < 128){ b1s[tid] = b1[tid]; b2s[tid] = b2[tid]; }
  __syncthreads();
  const int rowb = blockIdx.x * 64 + w * 16;

  f32x4 acc[8];
#pragma unroll
  for (int nt=0; nt<8; ++nt) acc[nt] = (f32x4){0.f,0.f,0.f,0.f};
#pragma unroll
  for (int kc=0; kc<3; ++kc){
    short8 a = *(const short8*)&sf[(size_t)(rowb + c)*96 + kc*32 + u*8];
#pragma unroll
    for (int nt=0; nt<8; ++nt){
      short8 bb = *(const short8*)&w1b[(nt*16+c)*96 + kc*32 + u*8];
      acc[nt] = __builtin_amdgcn_mfma_f32_16x16x32_bf16(a, bb, acc[nt], 0,0,0);
    }
  }
#pragma unroll
  for (int nt=0; nt<8; ++nt){
    float bias = b1s[nt*16+c];
#pragma unroll
    for (int q=0; q<4; ++q){
      float v = acc[nt][q] + bias; v = v > 0.f ? v : 0.f;
      hb[(u*4+q)*136 + nt*16 + c] = (unsigned short)f2bf_cvt(v);
    }
  }
  f32x4 acc2[8];
#pragma unroll
  for (int nt=0; nt<8; ++nt) acc2[nt] = (f32x4){0.f,0.f,0.f,0.f};
#pragma unroll
  for (int kc=0; kc<4; ++kc){
    short8 a = *(short8*)&hb[c*136 + kc*32 + u*8];
#pragma unroll
    for (int nt=0; nt<8; ++nt){
      short8 bb = *(const short8*)&w2b[(nt*16+c)*128 + kc*32 + u*8];
      acc2[nt] = __builtin_amdgcn_mfma_f32_16x16x32_bf16(a, bb, acc2[nt], 0,0,0);
    }
  }
#pragma unroll
  for (int nt=0; nt<8; ++nt){
    float bias = b2s[nt*16+c];
#pragma unroll
    for (int q=0; q<4; ++q){
      float v = acc2[nt][q] + bias; v = v > 0.f ? v : 0.f;
      int r = rowb + u*4 + q;
      combined[(size_t)(r >> 3)*1152 + 128 + (r & 7)*128 + nt*16 + c] = (unsigned short)f2bf_cvt(v);
    }
  }
}

// ---------------- head: 128 blocks x 256 thr (4 waves) ----------------
__global__ __launch_bounds__(256) void k_head(
    const unsigned short* __restrict__ combined,
    const unsigned short* __restrict__ wgt,
    const float* __restrict__ bf1, const float* __restrict__ bf2, const float* __restrict__ bf3,
    const float* __restrict__ lng, const float* __restrict__ lnb,
    float* __restrict__ out)
{
  __shared__ char smem[15104];
  const int tid = threadIdx.x, w = tid >> 6, u = (tid >> 4) & 3, c = tid & 15;
  unsigned short* f1b = (unsigned short*)smem;                 // [16][264]
  unsigned short* f2b = (unsigned short*)(smem + 8448);        // [16][136]
  float* bf1s = (float*)(smem + 12800); float* bf2s = (float*)(smem + 13824);
  float* bf3s = (float*)(smem + 14336);
  float* lngs = (float*)(smem + 14592); float* lnbs = (float*)(smem + 14848);
  const unsigned short* wf1b = wgt + 77824;
  const unsigned short* wf2b = wgt + 372736;
  const unsigned short* wf3b = wgt + 405504;
  bf1s[tid] = bf1[tid];
  if (tid < 128) bf2s[tid] = bf2[tid];
  if (tid < 64){ bf3s[tid] = bf3[tid]; lngs[tid] = lng[tid]; lnbs[tid] = lnb[tid]; }
  __syncthreads();
  const int rowb = blockIdx.x * 16;

  f32x4 acc[4];
#pragma unroll
  for (int i=0; i<4; ++i) acc[i] = (f32x4){0.f,0.f,0.f,0.f};
#pragma unroll 4
  for (int kc=0; kc<36; ++kc){
    short8 a = *(const short8*)&combined[(size_t)(rowb + c)*1152 + kc*32 + u*8];
#pragma unroll
    for (int i=0; i<4; ++i){
      int nt = w*4 + i;
      short8 bb = *(const short8*)&wf1b[(size_t)(nt*16+c)*1152 + kc*32 + u*8];
      acc[i] = __builtin_amdgcn_mfma_f32_16x16x32_bf16(a, bb, acc[i], 0,0,0);
    }
  }
#pragma unroll
  for (int i=0; i<4; ++i){
    int nt = w*4 + i;
    float bias = bf1s[nt*16+c];
#pragma unroll
    for (int q=0; q<4; ++q){
      float v = acc[i][q] + bias; v = v > 0.f ? v : 0.f;
      f1b[(u*4+q)*264 + nt*16 + c] = (unsigned short)f2bf_cvt(v);
    }
  }
  __syncthreads();

  f32x4 acc2[2];
#pragma unroll
  for (int i=0; i<2; ++i) acc2[i] = (f32x4){0.f,0.f,0.f,0.f};
#pragma unroll
  for (int kc=0; kc<8; ++kc){
    short8 a = *(short8*)&f1b[c*264 + kc*32 + u*8];
#pragma unroll
    for (int i=0; i<2; ++i){
      int nt = w*2 + i;
      short8 bb = *(const short8*)&wf2b[(nt*16+c)*256 + kc*32 + u*8];
      acc2[i] = __builtin_amdgcn_mfma_f32_16x16x32_bf16(a, bb, acc2[i], 0,0,0);
    }
  }
#pragma unroll
  for (int i=0; i<2; ++i){
    int nt = w*2 + i;
    float bias = bf2s[nt*16+c];
#pragma unroll
    for (int q=0; q<4; ++q){
      float v = acc2[i][q] + bias; v = v > 0.f ? v : 0.f;
      f2b[(u*4+q)*136 + nt*16 + c] = (unsigned short)f2bf_cvt(v);
    }
  }
  __syncthreads();

  f32x4 acc3[4];
#pragma unroll
  for (int nt=0; nt<4; ++nt) acc3[nt] = (f32x4){0.f,0.f,0.f,0.f};
#pragma unroll
  for (int kc=0; kc<4; ++kc){
    short8 a = *(short8*)&f2b[c*136 + kc*32 + u*8];
#pragma unroll
    for (int nt=0; nt<4; ++nt){
      short8 bb = *(const short8*)&wf3b[(nt*16+c)*128 + kc*32 + u*8];
      acc3[nt] = __builtin_amdgcn_mfma_f32_16x16x32_bf16(a, bb, acc3[nt], 0,0,0);
    }
  }
  if (w == 0){
    float v[4][4];
#pragma unroll
    for (int nt=0; nt<4; ++nt){
      float bias = bf3s[nt*16+c];
#pragma unroll
      for (int q=0; q<4; ++q){
        float t = acc3[nt][q] + bias; v[nt][q] = t > 0.f ? t : 0.f;
      }
    }
#pragma unroll
    for (int q=0; q<4; ++q){
      float p = v[0][q] + v[1][q] + v[2][q] + v[3][q];
      p += __shfl_xor(p, 1); p += __shfl_xor(p, 2); p += __shfl_xor(p, 4); p += __shfl_xor(p, 8);
      float mu = p * 0.015625f;
      float d0 = v[0][q]-mu, d1 = v[1][q]-mu, d2 = v[2][q]-mu, d3 = v[3][q]-mu;
      float p2 = d0*d0 + d1*d1 + d2*d2 + d3*d3;
      p2 += __shfl_xor(p2, 1); p2 += __shfl_xor(p2, 2); p2 += __shfl_xor(p2, 4); p2 += __shfl_xor(p2, 8);
      float rstd = __builtin_amdgcn_rsqf(p2 * 0.015625f + 1e-5f);
      int row = rowb + u*4 + q;
#pragma unroll
      for (int nt=0; nt<4; ++nt){
        int col = nt*16 + c;
        out[(size_t)row*64 + col] = (v[nt][q] - mu) * rstd * lngs[col] + lnbs[col];
      }
    }
  }
}

extern "C" void kernel_launch(void* const* d_in, const int* in_sizes, int n_in,
                              void* d_out, int out_size, void* d_ws, size_t ws_size,
                              hipStream_t stream)
{
  const float* ttraj = (const float*)d_in[0];
  const float* ntraj = (const float*)d_in[1];
  const float* rang  = (const float*)d_in[2];
  const float* nmask = (const float*)d_in[3];
  const float* Wih_t = (const float*)d_in[4];
  const float* Whh_t = (const float*)d_in[5];
  const float* bih_t = (const float*)d_in[6];
  const float* bhh_t = (const float*)d_in[7];
  const float* Wih_n = (const float*)d_in[8];
  const float* Whh_n = (const float*)d_in[9];
  const float* bih_n = (const float*)d_in[10];
  const float* bhh_n = (const float*)d_in[11];
  const float* W1  = (const float*)d_in[12];
  const float* b1  = (const float*)d_in[13];
  const float* W2  = (const float*)d_in[14];
  const float* b2  = (const float*)d_in[15];
  const float* Wf1 = (const float*)d_in[16];
  const float* bf1 = (const float*)d_in[17];
  const float* Wf2 = (const float*)d_in[18];
  const float* bf2 = (const float*)d_in[19];
  const float* Wf3 = (const float*)d_in[20];
  const float* bf3 = (const float*)d_in[21];
  const float* lng = (const float*)d_in[22];
  const float* lnb = (const float*)d_in[23];

  char* ws = (char*)d_ws;
  unsigned short* combined = (unsigned short*)ws;                  // [2048][1152] bf16
  unsigned short* sf       = (unsigned short*)(ws + 5242880);      // [16384][96] bf16
  unsigned short* wgt      = (unsigned short*)(ws + 8388608);      // bf16 weights (413696 u16)

  hipLaunchKernelGGL(k_gn, dim3(3664), dim3(256), 0, stream,
                     ttraj, ntraj, rang, nmask,
                     Wih_n, bih_n, bhh_n, Whh_n,
                     Whh_t, W1, W2, Wf1, Wf2, Wf3,
                     wgt, sf);
  hipLaunchKernelGGL(k_gru_t, dim3(128), dim3(256), 0, stream,
                     ttraj, Wih_t, bih_t, bhh_t, wgt, combined);
  hipLaunchKernelGGL(k_mlp12, dim3(256), dim3(256), 0, stream, sf, wgt, b1, b2, combined);
  hipLaunchKernelGGL(k_head, dim3(128), dim3(256), 0, stream,
                     combined, wgt, bf1, bf2, bf3, lng, lnb, (float*)d_out);
}

// Round 16
// 130.418 us; speedup vs baseline: 1.2920x; 1.0537x over previous
//
#include <hip/hip_runtime.h>

typedef __attribute__((ext_vector_type(8))) short short8;
typedef __attribute__((ext_vector_type(4))) float f32x4;

#define SGC (-1.44269504088896341f)   /* -log2(e): sigmoid prescale */
#define THC ( 2.88539008177792681f)   /* 2*log2(e): tanh prescale   */

__device__ __forceinline__ unsigned short f2bf(float f){
  unsigned u = __float_as_uint(f);
  return (unsigned short)((u + 0x7fffu + ((u >> 16) & 1u)) >> 16);
}
__device__ __forceinline__ float bf2f(unsigned short b){
  return __uint_as_float(((unsigned)b) << 16);
}
__device__ __forceinline__ unsigned f2bf_cvt(float f){
  unsigned r;
  asm("v_cvt_pk_bf16_f32 %0, %1, %1" : "=v"(r) : "v"(f));
  return r;
}
__device__ __forceinline__ unsigned f2bf_pk(float lo, float hi){
  unsigned r;
  asm("v_cvt_pk_bf16_f32 %0, %1, %2" : "=v"(r) : "v"(lo), "v"(hi));
  return r;
}

// wgt layout (u16 elems):
//   whhT_b [384*128]  @0        (PRESCALED: rows<256 *SGC, rows>=256 *THC)
//   W1b    [128*96]   @49152    (96 = 68 padded, zeros)
//   W2b    [128*128]  @61440
//   Wf1b   [256*1152] @77824
//   Wf2b   [128*256]  @372736
//   Wf3b   [64*128]   @405504   (total 413696 -> 1616 prep blocks)

// ---------------- merged: prep (blocks 0..1615) | neighbor GRU (1616..3663) ----------------
__global__ __launch_bounds__(256, 4) void k_gn(
    const float* __restrict__ ttraj, const float* __restrict__ ntraj,
    const float* __restrict__ rang,  const float* __restrict__ nmask,
    const float* __restrict__ Wih_n, const float* __restrict__ bih_n,
    const float* __restrict__ bhh_n, const float* __restrict__ Whh_n,
    const float* __restrict__ Whh_t, const float* __restrict__ W1,
    const float* __restrict__ W2,    const float* __restrict__ Wf1,
    const float* __restrict__ Wf2,   const float* __restrict__ Wf3,
    unsigned short* __restrict__ wgt,
    unsigned short* __restrict__ sf)             // [16384][96] bf16
{
  __shared__ char smem[20480];
  const int tid = threadIdx.x;

  if (blockIdx.x < 1616){
    // ================= prep: fp32 -> bf16 weights =================
    int i = blockIdx.x * 256 + tid;
    if (i < 49152){
      int g = i >> 7;
      float s = (g < 256) ? SGC : THC;
      wgt[i] = f2bf(Whh_t[i] * s); return;
    }
    i -= 49152;
    if (i < 12288){ int r = i / 96, cc = i % 96;
      wgt[49152 + i] = (cc < 68) ? f2bf(W1[r*68 + cc]) : (unsigned short)0; return; }
    i -= 12288;
    if (i < 16384){ wgt[61440 + i] = f2bf(W2[i]); return; }
    i -= 16384;
    if (i < 294912){ wgt[77824 + i] = f2bf(Wf1[i]); return; }
    i -= 294912;
    if (i < 32768){ wgt[372736 + i] = f2bf(Wf2[i]); return; }
    i -= 32768;
    if (i < 8192){ wgt[405504 + i] = f2bf(Wf3[i]); return; }
    return;
  }

  // ================= neighbor GRU (col-wave) + pooling =================
  const int b = blockIdx.x - 1616;
  const int w = tid >> 6, u = (tid >> 4) & 3, c = tid & 15;

  unsigned short* hb0 = (unsigned short*)smem;              // [64][72]
  unsigned short* hb1 = (unsigned short*)(smem + 9216);     // [64][72]
  unsigned* xpk = (unsigned*)(smem + 18432);                // [8][64] u32
  float* pool   = (float*)(smem + 18432);                   // alias (512 f32)

  // self-convert step-invariant B fragments (prescaled) from fp32
  short8 Bh[6], Bx[3];
#pragma unroll
  for (int k = 0; k < 3; ++k){           // 0=r, 1=z, 2=n
    float s = (k < 2) ? SGC : THC;
    const float* src = Whh_n + ((size_t)((k*4 + w)*16 + c))*64;
#pragma unroll
    for (int h = 0; h < 2; ++h){
      const float* p = src + h*32 + u*8;
      union { unsigned ui[4]; short8 s8; } t;
#pragma unroll
      for (int j = 0; j < 4; ++j) t.ui[j] = f2bf_pk(p[2*j]*s, p[2*j+1]*s);
      Bh[k*2+h] = t.s8;
    }
    int g = k*64 + w*16 + c;
    float bsum = ((k < 2) ? (bih_n[g] + bhh_n[g]) : bih_n[g]);
    union { unsigned ui[4]; short8 s8; } tx;
    tx.ui[0] = f2bf_pk(Wih_n[g*2]*s, Wih_n[g*2+1]*s);
    tx.ui[1] = f2bf_pk(bsum*s, 0.f);
    tx.ui[2] = 0u; tx.ui[3] = 0u;
    Bx[k] = tx.s8;
  }
  const float bh_ = bhh_n[128 + w*16 + c] * THC;

  {
    float4 v = ((const float4*)(ntraj + (size_t)b * 1024))[tid];
    int n = tid >> 2, p = (tid & 3) * 2;
    xpk[p*64 + n]     = f2bf_pk(v.x, v.y);
    xpk[(p+1)*64 + n] = f2bf_pk(v.z, v.w);
  }
  __syncthreads();

  float hcur[4][4];
#pragma unroll
  for (int sg=0; sg<4; ++sg)
#pragma unroll
    for (int q=0; q<4; ++q) hcur[sg][q] = 0.0f;

  const f32x4 zz = {0.f,0.f,0.f,0.f};

#pragma unroll 1
  for (int st = 0; st < 8; ++st){
    unsigned short* wbuf = (st & 1) ? hb1 : hb0;
    unsigned short* rbuf = (st & 1) ? hb0 : hb1;

    short8 a0s[4], a1s[4];
    unsigned xv[4];
#pragma unroll
    for (int sg = 0; sg < 4; ++sg){
      xv[sg] = xpk[st*64 + sg*16 + c];
      if (st > 0){
        a0s[sg] = *(short8*)&rbuf[(sg*16 + c)*72 + u*8];
        a1s[sg] = *(short8*)&rbuf[(sg*16 + c)*72 + 32 + u*8];
      }
    }

#pragma unroll
    for (int sg = 0; sg < 4; ++sg){
      union { unsigned ui[4]; short8 s8; } a2u;
      a2u.ui[0] = (u == 0) ? xv[sg] : 0u;
      a2u.ui[1] = (u == 0) ? 0x3F80u : 0u;   // bf16(1.0) in halfword 2
      a2u.ui[2] = 0u; a2u.ui[3] = 0u;
      short8 a2 = a2u.s8;

      f32x4 aR = __builtin_amdgcn_mfma_f32_16x16x32_bf16(a2, Bx[0], zz, 0,0,0);
      f32x4 aZ = __builtin_amdgcn_mfma_f32_16x16x32_bf16(a2, Bx[1], zz, 0,0,0);
      f32x4 aX = __builtin_amdgcn_mfma_f32_16x16x32_bf16(a2, Bx[2], zz, 0,0,0);
      f32x4 aN = zz;
      if (st > 0){
        aR = __builtin_amdgcn_mfma_f32_16x16x32_bf16(a0s[sg], Bh[0], aR, 0,0,0);
        aR = __builtin_amdgcn_mfma_f32_16x16x32_bf16(a1s[sg], Bh[1], aR, 0,0,0);
        aZ = __builtin_amdgcn_mfma_f32_16x16x32_bf16(a0s[sg], Bh[2], aZ, 0,0,0);
        aZ = __builtin_amdgcn_mfma_f32_16x16x32_bf16(a1s[sg], Bh[3], aZ, 0,0,0);
        aN = __builtin_amdgcn_mfma_f32_16x16x32_bf16(a0s[sg], Bh[4], aN, 0,0,0);
        aN = __builtin_amdgcn_mfma_f32_16x16x32_bf16(a1s[sg], Bh[5], aN, 0,0,0);
      }
#pragma unroll
      for (int q = 0; q < 4; ++q){
        float r = __builtin_amdgcn_rcpf(1.0f + __builtin_amdgcn_exp2f(aR[q]));
        float z = __builtin_amdgcn_rcpf(1.0f + __builtin_amdgcn_exp2f(aZ[q]));
        float hn = aN[q] + bh_;
        float pn = __builtin_fmaf(r, hn, aX[q]);
        float E = __builtin_amdgcn_exp2f(pn);
        float n = __builtin_fmaf(-2.0f, __builtin_amdgcn_rcpf(E + 1.0f), 1.0f);
        float hnew = __builtin_fmaf(z, hcur[sg][q] - n, n);
        hcur[sg][q] = hnew;
        wbuf[(sg*16 + u*4 + q)*72 + w*16 + c] = (unsigned short)f2bf_cvt(hnew);
      }
    }
    __syncthreads();
  }
  // final h (st=7) lives in hb1

  // ---- sector pooling ----
  if (tid < 64){
    int n = tid;
    const float* nb = ntraj + (size_t)b*1024 + n*16;
    float px = nb[14], py = nb[15];
    float vx = px - nb[12], vy = py - nb[13];
    float m   = nmask[(size_t)b*64 + n];
    float ang = rang[(size_t)b*64 + n];
    float tx = ttraj[(size_t)b*16 + 14], ty = ttraj[(size_t)b*16 + 15];
    float dx = px - tx, dy = py - ty;
    float dist = __builtin_amdgcn_sqrtf(dx*dx + dy*dy);
    int sid = (int)(ang / 0.78539816339744830962f);
    sid = sid < 0 ? 0 : (sid > 7 ? 7 : sid);
    bool valid = m > 0.0f;
    float wv = valid ? __builtin_amdgcn_exp2f(dist * -0.14426950408889634f) : 0.0f;
    pool[n]       = valid ? dist : 0.0f;
    pool[64 + n]  = valid ? vx   : 0.0f;
    pool[128 + n] = valid ? vy   : 0.0f;
    pool[192 + n] = wv;
    pool[256 + n] = valid ? (float)sid : -1.0f;
  }
  __syncthreads();
  if (tid < 8){
    int s = tid;
    float cnt=0.f, sd=0.f, sx=0.f, sy=0.f, sw=0.f;
#pragma unroll 4
    for (int n=0; n<64; ++n){
      if (pool[256+n] == (float)s){
        cnt += 1.f; sd += pool[n]; sx += pool[64+n]; sy += pool[128+n]; sw += pool[192+n];
      }
    }
    float inv = (cnt > 0.f) ? __builtin_amdgcn_rcpf(cnt) : 0.f;
    pool[320 + s] = cnt;
    pool[328 + s] = sd * inv;
    pool[336 + s] = sx * inv;
    pool[344 + s] = sy * inv;
    pool[352 + s] = __builtin_amdgcn_rcpf(sw + 1e-8f);
  }
  __syncthreads();
#pragma unroll
  for (int rep = 0; rep < 2; ++rep){
    int p = tid + rep*256;
    int s = p >> 6, h = p & 63;
    float fs = (float)s;
    float a = 0.f;
#pragma unroll 4
    for (int n = 0; n < 64; ++n){
      float wmv = (pool[256+n] == fs) ? pool[192+n] : 0.f;
      float nf  = bf2f(hb1[n*72 + h]);
      a += wmv * nf;
    }
    sf[((size_t)b*8 + s)*96 + 4 + h] = (unsigned short)f2bf_cvt(a * pool[352+s]);
  }
  if (tid < 32){
    int s = tid >> 2, cc = tid & 3;
    sf[((size_t)b*8 + s)*96 + cc] = (unsigned short)f2bf_cvt(pool[320 + cc*8 + s]);
  }
  if (tid < 224){
    int s = tid / 28, cc = 68 + tid % 28;
    sf[((size_t)b*8 + s)*96 + cc] = 0;
  }
}

// ---------------- merged: target GRU (blocks 0..127) | MLP1/2 (128..383) ----------------
// Independent work, disjoint column ranges of combined; both depend only on
// the k_gn launch. Merging overlaps gru_t's low-parallelism tail under mlp12.
__global__ __launch_bounds__(256) void k_gt_mlp(
    const float* __restrict__ ttraj,
    const float* __restrict__ Wih_t, const float* __restrict__ bih_t, const float* __restrict__ bhh_t,
    const unsigned short* __restrict__ sf,    // [16384][96]
    const unsigned short* __restrict__ wgt,
    const float* __restrict__ b1, const float* __restrict__ b2,
    unsigned short* __restrict__ combined)    // [2048][1152] bf16
{
  __shared__ char smem[18432];
  const int tid = threadIdx.x, w = tid >> 6, u = (tid >> 4) & 3, c = tid & 15;

  if (blockIdx.x < 128){
    // ================= target GRU =================
    unsigned short* hb0 = (unsigned short*)smem;             // [16][136]
    unsigned short* hb1 = (unsigned short*)(smem + 4352);    // [16][136]
    float* xs = (float*)(smem + 8704);                       // [16][16]

    xs[tid] = ttraj[(size_t)blockIdx.x*256 + tid];

    int ntg[6];
    ntg[0] = 2*w; ntg[1] = 2*w+1;
    ntg[2] = 8+2*w; ntg[3] = 9+2*w;
    ntg[4] = 16+2*w; ntg[5] = 17+2*w;

    short8 Bf[6][4];
#pragma unroll
    for (int lt2 = 0; lt2 < 6; ++lt2){
      const unsigned short* wp = wgt + (ntg[lt2]*16 + c)*128 + u*8;
#pragma unroll
      for (int kk = 0; kk < 4; ++kk)
        Bf[lt2][kk] = *(const short8*)(wp + kk*32);
    }

    float Wr0[2],Wr1[2],BR[2],Wz0[2],Wz1[2],BZ[2],Wn0[2],Wn1[2],BI[2],BH[2];
#pragma unroll
    for (int gt = 0; gt < 2; ++gt){
      int g = w*32 + gt*16 + c;
      Wr0[gt]=Wih_t[g*2]*SGC;        Wr1[gt]=Wih_t[g*2+1]*SGC;        BR[gt]=(bih_t[g]+bhh_t[g])*SGC;
      Wz0[gt]=Wih_t[(128+g)*2]*SGC;  Wz1[gt]=Wih_t[(128+g)*2+1]*SGC;  BZ[gt]=(bih_t[128+g]+bhh_t[128+g])*SGC;
      Wn0[gt]=Wih_t[(256+g)*2]*THC;  Wn1[gt]=Wih_t[(256+g)*2+1]*THC;  BI[gt]=bih_t[256+g]*THC; BH[gt]=bhh_t[256+g]*THC;
    }
    float hcur[2][4];
#pragma unroll
    for (int gt=0; gt<2; ++gt)
#pragma unroll
      for (int q=0; q<4; ++q) hcur[gt][q] = 0.0f;
    __syncthreads();

#pragma unroll 1
    for (int st = 0; st < 8; ++st){
      unsigned short* rbuf = (st & 1) ? hb0 : hb1;
      unsigned short* wbuf = (st & 1) ? hb1 : hb0;
      f32x4 acc[6];
      if (st > 0){
        short8 a0 = *(short8*)&rbuf[c*136 + u*8];
        short8 a1 = *(short8*)&rbuf[c*136 + 32 + u*8];
        short8 a2 = *(short8*)&rbuf[c*136 + 64 + u*8];
        short8 a3 = *(short8*)&rbuf[c*136 + 96 + u*8];
#pragma unroll
        for (int lt2 = 0; lt2 < 6; ++lt2){
          f32x4 t = {0.f,0.f,0.f,0.f};
          t = __builtin_amdgcn_mfma_f32_16x16x32_bf16(a0, Bf[lt2][0], t, 0,0,0);
          t = __builtin_amdgcn_mfma_f32_16x16x32_bf16(a1, Bf[lt2][1], t, 0,0,0);
          t = __builtin_amdgcn_mfma_f32_16x16x32_bf16(a2, Bf[lt2][2], t, 0,0,0);
          acc[lt2] = __builtin_amdgcn_mfma_f32_16x16x32_bf16(a3, Bf[lt2][3], t, 0,0,0);
        }
      } else {
#pragma unroll
        for (int lt2 = 0; lt2 < 6; ++lt2) acc[lt2] = (f32x4){0.f,0.f,0.f,0.f};
      }
#pragma unroll
      for (int gt = 0; gt < 2; ++gt){
#pragma unroll
        for (int q = 0; q < 4; ++q){
          int sq = u*4 + q;
          float x0 = xs[sq*16 + st*2], x1 = xs[sq*16 + st*2 + 1];
          float rp = __builtin_fmaf(Wr0[gt], x0, __builtin_fmaf(Wr1[gt], x1, acc[gt][q] + BR[gt]));
          float zp = __builtin_fmaf(Wz0[gt], x0, __builtin_fmaf(Wz1[gt], x1, acc[2+gt][q] + BZ[gt]));
          float r = __builtin_amdgcn_rcpf(1.0f + __builtin_amdgcn_exp2f(rp));
          float z = __builtin_amdgcn_rcpf(1.0f + __builtin_amdgcn_exp2f(zp));
          float hnv = acc[4+gt][q] + BH[gt];
          float pn = __builtin_fmaf(Wn0[gt], x0, __builtin_fmaf(Wn1[gt], x1, __builtin_fmaf(r, hnv, BI[gt])));
          float E = __builtin_amdgcn_exp2f(pn);
          float n = __builtin_fmaf(-2.0f, __builtin_amdgcn_rcpf(E + 1.0f), 1.0f);
          float hnew = __builtin_fmaf(z, hcur[gt][q] - n, n);
          hcur[gt][q] = hnew;
          if (st < 7){
            wbuf[sq*136 + w*32 + gt*16 + c] = (unsigned short)f2bf_cvt(hnew);
          } else {
            int row = blockIdx.x*16 + sq;
            combined[(size_t)row*1152 + w*32 + gt*16 + c] = (unsigned short)f2bf_cvt(hnew);
          }
        }
      }
      if (st < 7) __syncthreads();
    }
    return;
  }

  // ================= MLP1/MLP2 =================
  unsigned short* hb = (unsigned short*)smem + w * 2176;     // [16][136]/wave
  float* b1s = (float*)(smem + 17408);
  float* b2s = b1s + 128;
  const unsigned short* w1b = wgt + 49152;
  const unsigned short* w2b = wgt + 61440;
  if (tid < 128){ b1s[tid] = b1[tid]; b2s[tid] = b2[tid]; }
  __syncthreads();
  const int rowb = (blockIdx.x - 128) * 64 + w * 16;

  f32x4 acc[8];
#pragma unroll
  for (int nt=0; nt<8; ++nt) acc[nt] = (f32x4){0.f,0.f,0.f,0.f};
#pragma unroll
  for (int kc=0; kc<3; ++kc){
    short8 a = *(const short8*)&sf[(size_t)(rowb + c)*96 + kc*32 + u*8];
#pragma unroll
    for (int nt=0; nt<8; ++nt){
      short8 bb = *(const short8*)&w1b[(nt*16+c)*96 + kc*32 + u*8];
      acc[nt] = __builtin_amdgcn_mfma_f32_16x16x32_bf16(a, bb, acc[nt], 0,0,0);
    }
  }
#pragma unroll
  for (int nt=0; nt<8; ++nt){
    float bias = b1s[nt*16+c];
#pragma unroll
    for (int q=0; q<4; ++q){
      float v = acc[nt][q] + bias; v = v > 0.f ? v : 0.f;
      hb[(u*4+q)*136 + nt*16 + c] = (unsigned short)f2bf_cvt(v);
    }
  }
  f32x4 acc2[8];
#pragma unroll
  for (int nt=0; nt<8; ++nt) acc2[nt] = (f32x4){0.f,0.f,0.f,0.f};
#pragma unroll
  for (int kc=0; kc<4; ++kc){
    short8 a = *(short8*)&hb[c*136 + kc*32 + u*8];
#pragma unroll
    for (int nt=0; nt<8; ++nt){
      short8 bb = *(const short8*)&w2b[(nt*16+c)*128 + kc*32 + u*8];
      acc2[nt] = __builtin_amdgcn_mfma_f32_16x16x32_bf16(a, bb, acc2[nt], 0,0,0);
    }
  }
#pragma unroll
  for (int nt=0; nt<8; ++nt){
    float bias = b2s[nt*16+c];
#pragma unroll
    for (int q=0; q<4; ++q){
      float v = acc2[nt][q] + bias; v = v > 0.f ? v : 0.f;
      int r = rowb + u*4 + q;
      combined[(size_t)(r >> 3)*1152 + 128 + (r & 7)*128 + nt*16 + c] = (unsigned short)f2bf_cvt(v);
    }
  }
}

// ---------------- head: 128 blocks x 256 thr (4 waves) ----------------
__global__ __launch_bounds__(256) void k_head(
    const unsigned short* __restrict__ combined,
    const unsigned short* __restrict__ wgt,
    const float* __restrict__ bf1, const float* __restrict__ bf2, const float* __restrict__ bf3,
    const float* __restrict__ lng, const float* __restrict__ lnb,
    float* __restrict__ out)
{
  __shared__ char smem[15104];
  const int tid = threadIdx.x, w = tid >> 6, u = (tid >> 4) & 3, c = tid & 15;
  unsigned short* f1b = (unsigned short*)smem;                 // [16][264]
  unsigned short* f2b = (unsigned short*)(smem + 8448);        // [16][136]
  float* bf1s = (float*)(smem + 12800); float* bf2s = (float*)(smem + 13824);
  float* bf3s = (float*)(smem + 14336);
  float* lngs = (float*)(smem + 14592); float* lnbs = (float*)(smem + 14848);
  const unsigned short* wf1b = wgt + 77824;
  const unsigned short* wf2b = wgt + 372736;
  const unsigned short* wf3b = wgt + 405504;
  bf1s[tid] = bf1[tid];
  if (tid < 128) bf2s[tid] = bf2[tid];
  if (tid < 64){ bf3s[tid] = bf3[tid]; lngs[tid] = lng[tid]; lnbs[tid] = lnb[tid]; }
  __syncthreads();
  const int rowb = blockIdx.x * 16;

  f32x4 acc[4];
#pragma unroll
  for (int i=0; i<4; ++i) acc[i] = (f32x4){0.f,0.f,0.f,0.f};
#pragma unroll 4
  for (int kc=0; kc<36; ++kc){
    short8 a = *(const short8*)&combined[(size_t)(rowb + c)*1152 + kc*32 + u*8];
#pragma unroll
    for (int i=0; i<4; ++i){
      int nt = w*4 + i;
      short8 bb = *(const short8*)&wf1b[(size_t)(nt*16+c)*1152 + kc*32 + u*8];
      acc[i] = __builtin_amdgcn_mfma_f32_16x16x32_bf16(a, bb, acc[i], 0,0,0);
    }
  }
#pragma unroll
  for (int i=0; i<4; ++i){
    int nt = w*4 + i;
    float bias = bf1s[nt*16+c];
#pragma unroll
    for (int q=0; q<4; ++q){
      float v = acc[i][q] + bias; v = v > 0.f ? v : 0.f;
      f1b[(u*4+q)*264 + nt*16 + c] = (unsigned short)f2bf_cvt(v);
    }
  }
  __syncthreads();

  f32x4 acc2[2];
#pragma unroll
  for (int i=0; i<2; ++i) acc2[i] = (f32x4){0.f,0.f,0.f,0.f};
#pragma unroll
  for (int kc=0; kc<8; ++kc){
    short8 a = *(short8*)&f1b[c*264 + kc*32 + u*8];
#pragma unroll
    for (int i=0; i<2; ++i){
      int nt = w*2 + i;
      short8 bb = *(const short8*)&wf2b[(nt*16+c)*256 + kc*32 + u*8];
      acc2[i] = __builtin_amdgcn_mfma_f32_16x16x32_bf16(a, bb, acc2[i], 0,0,0);
    }
  }
#pragma unroll
  for (int i=0; i<2; ++i){
    int nt = w*2 + i;
    float bias = bf2s[nt*16+c];
#pragma unroll
    for (int q=0; q<4; ++q){
      float v = acc2[i][q] + bias; v = v > 0.f ? v : 0.f;
      f2b[(u*4+q)*136 + nt*16 + c] = (unsigned short)f2bf_cvt(v);
    }
  }
  __syncthreads();

  f32x4 acc3[4];
#pragma unroll
  for (int nt=0; nt<4; ++nt) acc3[nt] = (f32x4){0.f,0.f,0.f,0.f};
#pragma unroll
  for (int kc=0; kc<4; ++kc){
    short8 a = *(short8*)&f2b[c*136 + kc*32 + u*8];
#pragma unroll
    for (int nt=0; nt<4; ++nt){
      short8 bb = *(const short8*)&wf3b[(nt*16+c)*128 + kc*32 + u*8];
      acc3[nt] = __builtin_amdgcn_mfma_f32_16x16x32_bf16(a, bb, acc3[nt], 0,0,0);
    }
  }
  if (w == 0){
    float v[4][4];
#pragma unroll
    for (int nt=0; nt<4; ++nt){
      float bias = bf3s[nt*16+c];
#pragma unroll
      for (int q=0; q<4; ++q){
        float t = acc3[nt][q] + bias; v[nt][q] = t > 0.f ? t : 0.f;
      }
    }
#pragma unroll
    for (int q=0; q<4; ++q){
      float p = v[0][q] + v[1][q] + v[2][q] + v[3][q];
      p += __shfl_xor(p, 1); p += __shfl_xor(p, 2); p += __shfl_xor(p, 4); p += __shfl_xor(p, 8);
      float mu = p * 0.015625f;
      float d0 = v[0][q]-mu, d1 = v[1][q]-mu, d2 = v[2][q]-mu, d3 = v[3][q]-mu;
      float p2 = d0*d0 + d1*d1 + d2*d2 + d3*d3;
      p2 += __shfl_xor(p2, 1); p2 += __shfl_xor(p2, 2); p2 += __shfl_xor(p2, 4); p2 += __shfl_xor(p2, 8);
      float rstd = __builtin_amdgcn_rsqf(p2 * 0.015625f + 1e-5f);
      int row = rowb + u*4 + q;
#pragma unroll
      for (int nt=0; nt<4; ++nt){
        int col = nt*16 + c;
        out[(size_t)row*64 + col] = (v[nt][q] - mu) * rstd * lngs[col] + lnbs[col];
      }
    }
  }
}

extern "C" void kernel_launch(void* const* d_in, const int* in_sizes, int n_in,
                              void* d_out, int out_size, void* d_ws, size_t ws_size,
                              hipStream_t stream)
{
  const float* ttraj = (const float*)d_in[0];
  const float* ntraj = (const float*)d_in[1];
  const float* rang  = (const float*)d_in[2];
  const float* nmask = (const float*)d_in[3];
  const float* Wih_t = (const float*)d_in[4];
  const float* Whh_t = (const float*)d_in[5];
  const float* bih_t = (const float*)d_in[6];
  const float* bhh_t = (const float*)d_in[7];
  const float* Wih_n = (const float*)d_in[8];
  const float* Whh_n = (const float*)d_in[9];
  const float* bih_n = (const float*)d_in[10];
  const float* bhh_n = (const float*)d_in[11];
  const float* W1  = (const float*)d_in[12];
  const float* b1  = (const float*)d_in[13];
  const float* W2  = (const float*)d_in[14];
  const float* b2  = (const float*)d_in[15];
  const float* Wf1 = (const float*)d_in[16];
  const float* bf1 = (const float*)d_in[17];
  const float* Wf2 = (const float*)d_in[18];
  const float* bf2 = (const float*)d_in[19];
  const float* Wf3 = (const float*)d_in[20];
  const float* bf3 = (const float*)d_in[21];
  const float* lng = (const float*)d_in[22];
  const float* lnb = (const float*)d_in[23];

  char* ws = (char*)d_ws;
  unsigned short* combined = (unsigned short*)ws;                  // [2048][1152] bf16
  unsigned short* sf       = (unsigned short*)(ws + 5242880);      // [16384][96] bf16
  unsigned short* wgt      = (unsigned short*)(ws + 8388608);      // bf16 weights (413696 u16)

  hipLaunchKernelGGL(k_gn, dim3(3664), dim3(256), 0, stream,
                     ttraj, ntraj, rang, nmask,
                     Wih_n, bih_n, bhh_n, Whh_n,
                     Whh_t, W1, W2, Wf1, Wf2, Wf3,
                     wgt, sf);
  hipLaunchKernelGGL(k_gt_mlp, dim3(384), dim3(256), 0, stream,
                     ttraj, Wih_t, bih_t, bhh_t, sf, wgt, b1, b2, combined);
  hipLaunchKernelGGL(k_head, dim3(128), dim3(256), 0, stream,
                     combined, wgt, bf1, bf2, bf3, lng, lnb, (float*)d_out);
}

// Round 17
// 130.371 us; speedup vs baseline: 1.2925x; 1.0004x over previous
//
#include <hip/hip_runtime.h>

typedef __attribute__((ext_vector_type(8))) short short8;
typedef __attribute__((ext_vector_type(4))) float f32x4;

#define SGC (-1.44269504088896341f)   /* -log2(e): sigmoid prescale */
#define THC ( 2.88539008177792681f)   /* 2*log2(e): tanh prescale   */

__device__ __forceinline__ unsigned short f2bf(float f){
  unsigned u = __float_as_uint(f);
  return (unsigned short)((u + 0x7fffu + ((u >> 16) & 1u)) >> 16);
}
__device__ __forceinline__ float bf2f(unsigned short b){
  return __uint_as_float(((unsigned)b) << 16);
}
__device__ __forceinline__ unsigned f2bf_cvt(float f){
  unsigned r;
  asm("v_cvt_pk_bf16_f32 %0, %1, %1" : "=v"(r) : "v"(f));
  return r;
}
__device__ __forceinline__ unsigned f2bf_pk(float lo, float hi){
  unsigned r;
  asm("v_cvt_pk_bf16_f32 %0, %1, %2" : "=v"(r) : "v"(lo), "v"(hi));
  return r;
}

// wgt layout (u16 elems):
//   whhT_b [384*128]  @0        (PRESCALED: rows<256 *SGC, rows>=256 *THC)
//   W1b    [128*96]   @49152    (96 = 68 padded, zeros)
//   W2b    [128*128]  @61440
//   Wf1b   [256*1152] @77824
//   Wf2b   [128*256]  @372736
//   Wf3b   [64*128]   @405504   (total 413696 -> 1616 prep blocks)

// ---------------- merged: prep (blocks 0..1615) | neighbor GRU (1616..3663) ----------------
__global__ __launch_bounds__(256, 4) void k_gn(
    const float* __restrict__ ttraj, const float* __restrict__ ntraj,
    const float* __restrict__ rang,  const float* __restrict__ nmask,
    const float* __restrict__ Wih_n, const float* __restrict__ bih_n,
    const float* __restrict__ bhh_n, const float* __restrict__ Whh_n,
    const float* __restrict__ Whh_t, const float* __restrict__ W1,
    const float* __restrict__ W2,    const float* __restrict__ Wf1,
    const float* __restrict__ Wf2,   const float* __restrict__ Wf3,
    unsigned short* __restrict__ wgt,
    unsigned short* __restrict__ sf)             // [16384][96] bf16
{
  __shared__ char smem[20480];
  const int tid = threadIdx.x;

  if (blockIdx.x < 1616){
    // ================= prep: fp32 -> bf16 weights =================
    int i = blockIdx.x * 256 + tid;
    if (i < 49152){
      int g = i >> 7;
      float s = (g < 256) ? SGC : THC;
      wgt[i] = f2bf(Whh_t[i] * s); return;
    }
    i -= 49152;
    if (i < 12288){ int r = i / 96, cc = i % 96;
      wgt[49152 + i] = (cc < 68) ? f2bf(W1[r*68 + cc]) : (unsigned short)0; return; }
    i -= 12288;
    if (i < 16384){ wgt[61440 + i] = f2bf(W2[i]); return; }
    i -= 16384;
    if (i < 294912){ wgt[77824 + i] = f2bf(Wf1[i]); return; }
    i -= 294912;
    if (i < 32768){ wgt[372736 + i] = f2bf(Wf2[i]); return; }
    i -= 32768;
    if (i < 8192){ wgt[405504 + i] = f2bf(Wf3[i]); return; }
    return;
  }

  // ================= neighbor GRU (col-wave) + pooling =================
  const int b = blockIdx.x - 1616;
  const int w = tid >> 6, u = (tid >> 4) & 3, c = tid & 15;

  unsigned short* hb0 = (unsigned short*)smem;              // [64][72]
  unsigned short* hb1 = (unsigned short*)(smem + 9216);     // [64][72]
  unsigned* xpk = (unsigned*)(smem + 18432);                // [8][64] u32
  float* pool   = (float*)(smem + 18432);                   // alias (512 f32)

  // self-convert step-invariant B fragments (prescaled) from fp32
  short8 Bh[6], Bx[3];
#pragma unroll
  for (int k = 0; k < 3; ++k){           // 0=r, 1=z, 2=n
    float s = (k < 2) ? SGC : THC;
    const float* src = Whh_n + ((size_t)((k*4 + w)*16 + c))*64;
#pragma unroll
    for (int h = 0; h < 2; ++h){
      const float* p = src + h*32 + u*8;
      union { unsigned ui[4]; short8 s8; } t;
#pragma unroll
      for (int j = 0; j < 4; ++j) t.ui[j] = f2bf_pk(p[2*j]*s, p[2*j+1]*s);
      Bh[k*2+h] = t.s8;
    }
    int g = k*64 + w*16 + c;
    float bsum = ((k < 2) ? (bih_n[g] + bhh_n[g]) : bih_n[g]);
    union { unsigned ui[4]; short8 s8; } tx;
    tx.ui[0] = f2bf_pk(Wih_n[g*2]*s, Wih_n[g*2+1]*s);
    tx.ui[1] = f2bf_pk(bsum*s, 0.f);
    tx.ui[2] = 0u; tx.ui[3] = 0u;
    Bx[k] = tx.s8;
  }
  const float bh_ = bhh_n[128 + w*16 + c] * THC;

  {
    float4 v = ((const float4*)(ntraj + (size_t)b * 1024))[tid];
    int n = tid >> 2, p = (tid & 3) * 2;
    xpk[p*64 + n]     = f2bf_pk(v.x, v.y);
    xpk[(p+1)*64 + n] = f2bf_pk(v.z, v.w);
  }
  __syncthreads();

  float hcur[4][4];
#pragma unroll
  for (int sg=0; sg<4; ++sg)
#pragma unroll
    for (int q=0; q<4; ++q) hcur[sg][q] = 0.0f;

  const f32x4 zz = {0.f,0.f,0.f,0.f};

#pragma unroll 1
  for (int st = 0; st < 8; ++st){
    unsigned short* wbuf = (st & 1) ? hb1 : hb0;
    unsigned short* rbuf = (st & 1) ? hb0 : hb1;

    short8 a0s[4], a1s[4];
    unsigned xv[4];
#pragma unroll
    for (int sg = 0; sg < 4; ++sg){
      xv[sg] = xpk[st*64 + sg*16 + c];
      if (st > 0){
        a0s[sg] = *(short8*)&rbuf[(sg*16 + c)*72 + u*8];
        a1s[sg] = *(short8*)&rbuf[(sg*16 + c)*72 + 32 + u*8];
      }
    }

#pragma unroll
    for (int sg = 0; sg < 4; ++sg){
      union { unsigned ui[4]; short8 s8; } a2u;
      a2u.ui[0] = (u == 0) ? xv[sg] : 0u;
      a2u.ui[1] = (u == 0) ? 0x3F80u : 0u;   // bf16(1.0) in halfword 2
      a2u.ui[2] = 0u; a2u.ui[3] = 0u;
      short8 a2 = a2u.s8;

      f32x4 aR = __builtin_amdgcn_mfma_f32_16x16x32_bf16(a2, Bx[0], zz, 0,0,0);
      f32x4 aZ = __builtin_amdgcn_mfma_f32_16x16x32_bf16(a2, Bx[1], zz, 0,0,0);
      f32x4 aX = __builtin_amdgcn_mfma_f32_16x16x32_bf16(a2, Bx[2], zz, 0,0,0);
      f32x4 aN = zz;
      if (st > 0){
        aR = __builtin_amdgcn_mfma_f32_16x16x32_bf16(a0s[sg], Bh[0], aR, 0,0,0);
        aR = __builtin_amdgcn_mfma_f32_16x16x32_bf16(a1s[sg], Bh[1], aR, 0,0,0);
        aZ = __builtin_amdgcn_mfma_f32_16x16x32_bf16(a0s[sg], Bh[2], aZ, 0,0,0);
        aZ = __builtin_amdgcn_mfma_f32_16x16x32_bf16(a1s[sg], Bh[3], aZ, 0,0,0);
        aN = __builtin_amdgcn_mfma_f32_16x16x32_bf16(a0s[sg], Bh[4], aN, 0,0,0);
        aN = __builtin_amdgcn_mfma_f32_16x16x32_bf16(a1s[sg], Bh[5], aN, 0,0,0);
      }
#pragma unroll
      for (int q = 0; q < 4; ++q){
        float r = __builtin_amdgcn_rcpf(1.0f + __builtin_amdgcn_exp2f(aR[q]));
        float z = __builtin_amdgcn_rcpf(1.0f + __builtin_amdgcn_exp2f(aZ[q]));
        float hn = aN[q] + bh_;
        float pn = __builtin_fmaf(r, hn, aX[q]);
        float E = __builtin_amdgcn_exp2f(pn);
        float n = __builtin_fmaf(-2.0f, __builtin_amdgcn_rcpf(E + 1.0f), 1.0f);
        float hnew = __builtin_fmaf(z, hcur[sg][q] - n, n);
        hcur[sg][q] = hnew;
        wbuf[(sg*16 + u*4 + q)*72 + w*16 + c] = (unsigned short)f2bf_cvt(hnew);
      }
    }
    __syncthreads();
  }
  // final h (st=7) lives in hb1

  // ---- sector pooling ----
  if (tid < 64){
    int n = tid;
    const float* nb = ntraj + (size_t)b*1024 + n*16;
    float px = nb[14], py = nb[15];
    float vx = px - nb[12], vy = py - nb[13];
    float m   = nmask[(size_t)b*64 + n];
    float ang = rang[(size_t)b*64 + n];
    float tx = ttraj[(size_t)b*16 + 14], ty = ttraj[(size_t)b*16 + 15];
    float dx = px - tx, dy = py - ty;
    float dist = __builtin_amdgcn_sqrtf(dx*dx + dy*dy);
    int sid = (int)(ang / 0.78539816339744830962f);
    sid = sid < 0 ? 0 : (sid > 7 ? 7 : sid);
    bool valid = m > 0.0f;
    float wv = valid ? __builtin_amdgcn_exp2f(dist * -0.14426950408889634f) : 0.0f;
    pool[n]       = valid ? dist : 0.0f;
    pool[64 + n]  = valid ? vx   : 0.0f;
    pool[128 + n] = valid ? vy   : 0.0f;
    pool[192 + n] = wv;
    pool[256 + n] = valid ? (float)sid : -1.0f;
  }
  __syncthreads();
  if (tid < 8){
    int s = tid;
    float cnt=0.f, sd=0.f, sx=0.f, sy=0.f, sw=0.f;
#pragma unroll 4
    for (int n=0; n<64; ++n){
      if (pool[256+n] == (float)s){
        cnt += 1.f; sd += pool[n]; sx += pool[64+n]; sy += pool[128+n]; sw += pool[192+n];
      }
    }
    float inv = (cnt > 0.f) ? __builtin_amdgcn_rcpf(cnt) : 0.f;
    pool[320 + s] = cnt;
    pool[328 + s] = sd * inv;
    pool[336 + s] = sx * inv;
    pool[344 + s] = sy * inv;
    pool[352 + s] = __builtin_amdgcn_rcpf(sw + 1e-8f);
  }
  __syncthreads();
#pragma unroll
  for (int rep = 0; rep < 2; ++rep){
    int p = tid + rep*256;
    int s = p >> 6, h = p & 63;
    float fs = (float)s;
    float a = 0.f;
#pragma unroll 4
    for (int n = 0; n < 64; ++n){
      float wmv = (pool[256+n] == fs) ? pool[192+n] : 0.f;
      float nf  = bf2f(hb1[n*72 + h]);
      a += wmv * nf;
    }
    sf[((size_t)b*8 + s)*96 + 4 + h] = (unsigned short)f2bf_cvt(a * pool[352+s]);
  }
  if (tid < 32){
    int s = tid >> 2, cc = tid & 3;
    sf[((size_t)b*8 + s)*96 + cc] = (unsigned short)f2bf_cvt(pool[320 + cc*8 + s]);
  }
  if (tid < 224){
    int s = tid / 28, cc = 68 + tid % 28;
    sf[((size_t)b*8 + s)*96 + cc] = 0;
  }
}

// ---------------- merged: target GRU (blocks 0..127) | MLP1/2 (128..383) ----------------
__global__ __launch_bounds__(256) void k_gt_mlp(
    const float* __restrict__ ttraj,
    const float* __restrict__ Wih_t, const float* __restrict__ bih_t, const float* __restrict__ bhh_t,
    const unsigned short* __restrict__ sf,    // [16384][96]
    const unsigned short* __restrict__ wgt,
    const float* __restrict__ b1, const float* __restrict__ b2,
    unsigned short* __restrict__ combined)    // [2048][1152] bf16
{
  __shared__ char smem[18432];
  const int tid = threadIdx.x, w = tid >> 6, u = (tid >> 4) & 3, c = tid & 15;

  if (blockIdx.x < 128){
    // ================= target GRU =================
    unsigned short* hb0 = (unsigned short*)smem;             // [16][136]
    unsigned short* hb1 = (unsigned short*)(smem + 4352);    // [16][136]
    float* xs = (float*)(smem + 8704);                       // [16][16]

    xs[tid] = ttraj[(size_t)blockIdx.x*256 + tid];

    int ntg[6];
    ntg[0] = 2*w; ntg[1] = 2*w+1;
    ntg[2] = 8+2*w; ntg[3] = 9+2*w;
    ntg[4] = 16+2*w; ntg[5] = 17+2*w;

    short8 Bf[6][4];
#pragma unroll
    for (int lt2 = 0; lt2 < 6; ++lt2){
      const unsigned short* wp = wgt + (ntg[lt2]*16 + c)*128 + u*8;
#pragma unroll
      for (int kk = 0; kk < 4; ++kk)
        Bf[lt2][kk] = *(const short8*)(wp + kk*32);
    }

    float Wr0[2],Wr1[2],BR[2],Wz0[2],Wz1[2],BZ[2],Wn0[2],Wn1[2],BI[2],BH[2];
#pragma unroll
    for (int gt = 0; gt < 2; ++gt){
      int g = w*32 + gt*16 + c;
      Wr0[gt]=Wih_t[g*2]*SGC;        Wr1[gt]=Wih_t[g*2+1]*SGC;        BR[gt]=(bih_t[g]+bhh_t[g])*SGC;
      Wz0[gt]=Wih_t[(128+g)*2]*SGC;  Wz1[gt]=Wih_t[(128+g)*2+1]*SGC;  BZ[gt]=(bih_t[128+g]+bhh_t[128+g])*SGC;
      Wn0[gt]=Wih_t[(256+g)*2]*THC;  Wn1[gt]=Wih_t[(256+g)*2+1]*THC;  BI[gt]=bih_t[256+g]*THC; BH[gt]=bhh_t[256+g]*THC;
    }
    float hcur[2][4];
#pragma unroll
    for (int gt=0; gt<2; ++gt)
#pragma unroll
      for (int q=0; q<4; ++q) hcur[gt][q] = 0.0f;
    __syncthreads();

#pragma unroll 1
    for (int st = 0; st < 8; ++st){
      unsigned short* rbuf = (st & 1) ? hb0 : hb1;
      unsigned short* wbuf = (st & 1) ? hb1 : hb0;
      f32x4 acc[6];
      if (st > 0){
        short8 a0 = *(short8*)&rbuf[c*136 + u*8];
        short8 a1 = *(short8*)&rbuf[c*136 + 32 + u*8];
        short8 a2 = *(short8*)&rbuf[c*136 + 64 + u*8];
        short8 a3 = *(short8*)&rbuf[c*136 + 96 + u*8];
#pragma unroll
        for (int lt2 = 0; lt2 < 6; ++lt2){
          f32x4 t = {0.f,0.f,0.f,0.f};
          t = __builtin_amdgcn_mfma_f32_16x16x32_bf16(a0, Bf[lt2][0], t, 0,0,0);
          t = __builtin_amdgcn_mfma_f32_16x16x32_bf16(a1, Bf[lt2][1], t, 0,0,0);
          t = __builtin_amdgcn_mfma_f32_16x16x32_bf16(a2, Bf[lt2][2], t, 0,0,0);
          acc[lt2] = __builtin_amdgcn_mfma_f32_16x16x32_bf16(a3, Bf[lt2][3], t, 0,0,0);
        }
      } else {
#pragma unroll
        for (int lt2 = 0; lt2 < 6; ++lt2) acc[lt2] = (f32x4){0.f,0.f,0.f,0.f};
      }
#pragma unroll
      for (int gt = 0; gt < 2; ++gt){
#pragma unroll
        for (int q = 0; q < 4; ++q){
          int sq = u*4 + q;
          float x0 = xs[sq*16 + st*2], x1 = xs[sq*16 + st*2 + 1];
          float rp = __builtin_fmaf(Wr0[gt], x0, __builtin_fmaf(Wr1[gt], x1, acc[gt][q] + BR[gt]));
          float zp = __builtin_fmaf(Wz0[gt], x0, __builtin_fmaf(Wz1[gt], x1, acc[2+gt][q] + BZ[gt]));
          float r = __builtin_amdgcn_rcpf(1.0f + __builtin_amdgcn_exp2f(rp));
          float z = __builtin_amdgcn_rcpf(1.0f + __builtin_amdgcn_exp2f(zp));
          float hnv = acc[4+gt][q] + BH[gt];
          float pn = __builtin_fmaf(Wn0[gt], x0, __builtin_fmaf(Wn1[gt], x1, __builtin_fmaf(r, hnv, BI[gt])));
          float E = __builtin_amdgcn_exp2f(pn);
          float n = __builtin_fmaf(-2.0f, __builtin_amdgcn_rcpf(E + 1.0f), 1.0f);
          float hnew = __builtin_fmaf(z, hcur[gt][q] - n, n);
          hcur[gt][q] = hnew;
          if (st < 7){
            wbuf[sq*136 + w*32 + gt*16 + c] = (unsigned short)f2bf_cvt(hnew);
          } else {
            int row = blockIdx.x*16 + sq;
            combined[(size_t)row*1152 + w*32 + gt*16 + c] = (unsigned short)f2bf_cvt(hnew);
          }
        }
      }
      if (st < 7) __syncthreads();
    }
    return;
  }

  // ================= MLP1/MLP2 =================
  unsigned short* hb = (unsigned short*)smem + w * 2176;     // [16][136]/wave
  float* b1s = (float*)(smem + 17408);
  float* b2s = b1s + 128;
  const unsigned short* w1b = wgt + 49152;
  const unsigned short* w2b = wgt + 61440;
  if (tid < 128){ b1s[tid] = b1[tid]; b2s[tid] = b2[tid]; }
  __syncthreads();
  const int rowb = (blockIdx.x - 128) * 64 + w * 16;

  f32x4 acc[8];
#pragma unroll
  for (int nt=0; nt<8; ++nt) acc[nt] = (f32x4){0.f,0.f,0.f,0.f};
#pragma unroll
  for (int kc=0; kc<3; ++kc){
    short8 a = *(const short8*)&sf[(size_t)(rowb + c)*96 + kc*32 + u*8];
#pragma unroll
    for (int nt=0; nt<8; ++nt){
      short8 bb = *(const short8*)&w1b[(nt*16+c)*96 + kc*32 + u*8];
      acc[nt] = __builtin_amdgcn_mfma_f32_16x16x32_bf16(a, bb, acc[nt], 0,0,0);
    }
  }
#pragma unroll
  for (int nt=0; nt<8; ++nt){
    float bias = b1s[nt*16+c];
#pragma unroll
    for (int q=0; q<4; ++q){
      float v = acc[nt][q] + bias; v = v > 0.f ? v : 0.f;
      hb[(u*4+q)*136 + nt*16 + c] = (unsigned short)f2bf_cvt(v);
    }
  }
  f32x4 acc2[8];
#pragma unroll
  for (int nt=0; nt<8; ++nt) acc2[nt] = (f32x4){0.f,0.f,0.f,0.f};
#pragma unroll
  for (int kc=0; kc<4; ++kc){
    short8 a = *(short8*)&hb[c*136 + kc*32 + u*8];
#pragma unroll
    for (int nt=0; nt<8; ++nt){
      short8 bb = *(const short8*)&w2b[(nt*16+c)*128 + kc*32 + u*8];
      acc2[nt] = __builtin_amdgcn_mfma_f32_16x16x32_bf16(a, bb, acc2[nt], 0,0,0);
    }
  }
#pragma unroll
  for (int nt=0; nt<8; ++nt){
    float bias = b2s[nt*16+c];
#pragma unroll
    for (int q=0; q<4; ++q){
      float v = acc2[nt][q] + bias; v = v > 0.f ? v : 0.f;
      int r = rowb + u*4 + q;
      combined[(size_t)(r >> 3)*1152 + 128 + (r & 7)*128 + nt*16 + c] = (unsigned short)f2bf_cvt(v);
    }
  }
}

// ---------------- head: 256 blocks x 256 thr, 8 rows/block ----------------
// Widened from 128 blocks (half-idle GPU, latency-bound on Wf1 B-frag loads)
// to 256 blocks: A-rows c>=8 are neighbors' rows (clamped at array end),
// results for local rows 8..15 computed but never stored.
__global__ __launch_bounds__(256) void k_head(
    const unsigned short* __restrict__ combined,
    const unsigned short* __restrict__ wgt,
    const float* __restrict__ bf1, const float* __restrict__ bf2, const float* __restrict__ bf3,
    const float* __restrict__ lng, const float* __restrict__ lnb,
    float* __restrict__ out)
{
  __shared__ char smem[15104];
  const int tid = threadIdx.x, w = tid >> 6, u = (tid >> 4) & 3, c = tid & 15;
  unsigned short* f1b = (unsigned short*)smem;                 // [16][264]
  unsigned short* f2b = (unsigned short*)(smem + 8448);        // [16][136]
  float* bf1s = (float*)(smem + 12800); float* bf2s = (float*)(smem + 13824);
  float* bf3s = (float*)(smem + 14336);
  float* lngs = (float*)(smem + 14592); float* lnbs = (float*)(smem + 14848);
  const unsigned short* wf1b = wgt + 77824;
  const unsigned short* wf2b = wgt + 372736;
  const unsigned short* wf3b = wgt + 405504;
  bf1s[tid] = bf1[tid];
  if (tid < 128) bf2s[tid] = bf2[tid];
  if (tid < 64){ bf3s[tid] = bf3[tid]; lngs[tid] = lng[tid]; lnbs[tid] = lnb[tid]; }
  __syncthreads();
  const int rowb = blockIdx.x * 8;                 // 8 valid rows per block

  // A-row for lane: clamp (lanes c>=8 read beyond this block's rows; values
  // only affect local rows 8..15 which are never stored)
  int arow = rowb + c; if (arow > 2047) arow = 2047;

  f32x4 acc[4];
#pragma unroll
  for (int i=0; i<4; ++i) acc[i] = (f32x4){0.f,0.f,0.f,0.f};
#pragma unroll 4
  for (int kc=0; kc<36; ++kc){
    short8 a = *(const short8*)&combined[(size_t)arow*1152 + kc*32 + u*8];
#pragma unroll
    for (int i=0; i<4; ++i){
      int nt = w*4 + i;
      short8 bb = *(const short8*)&wf1b[(size_t)(nt*16+c)*1152 + kc*32 + u*8];
      acc[i] = __builtin_amdgcn_mfma_f32_16x16x32_bf16(a, bb, acc[i], 0,0,0);
    }
  }
#pragma unroll
  for (int i=0; i<4; ++i){
    int nt = w*4 + i;
    float bias = bf1s[nt*16+c];
#pragma unroll
    for (int q=0; q<4; ++q){
      float v = acc[i][q] + bias; v = v > 0.f ? v : 0.f;
      f1b[(u*4+q)*264 + nt*16 + c] = (unsigned short)f2bf_cvt(v);
    }
  }
  __syncthreads();

  f32x4 acc2[2];
#pragma unroll
  for (int i=0; i<2; ++i) acc2[i] = (f32x4){0.f,0.f,0.f,0.f};
#pragma unroll
  for (int kc=0; kc<8; ++kc){
    short8 a = *(short8*)&f1b[c*264 + kc*32 + u*8];
#pragma unroll
    for (int i=0; i<2; ++i){
      int nt = w*2 + i;
      short8 bb = *(const short8*)&wf2b[(nt*16+c)*256 + kc*32 + u*8];
      acc2[i] = __builtin_amdgcn_mfma_f32_16x16x32_bf16(a, bb, acc2[i], 0,0,0);
    }
  }
#pragma unroll
  for (int i=0; i<2; ++i){
    int nt = w*2 + i;
    float bias = bf2s[nt*16+c];
#pragma unroll
    for (int q=0; q<4; ++q){
      float v = acc2[i][q] + bias; v = v > 0.f ? v : 0.f;
      f2b[(u*4+q)*136 + nt*16 + c] = (unsigned short)f2bf_cvt(v);
    }
  }
  __syncthreads();

  f32x4 acc3[4];
#pragma unroll
  for (int nt=0; nt<4; ++nt) acc3[nt] = (f32x4){0.f,0.f,0.f,0.f};
#pragma unroll
  for (int kc=0; kc<4; ++kc){
    short8 a = *(short8*)&f2b[c*136 + kc*32 + u*8];
#pragma unroll
    for (int nt=0; nt<4; ++nt){
      short8 bb = *(const short8*)&wf3b[(nt*16+c)*128 + kc*32 + u*8];
      acc3[nt] = __builtin_amdgcn_mfma_f32_16x16x32_bf16(a, bb, acc3[nt], 0,0,0);
    }
  }
  if (w == 0){
    float v[4][4];
#pragma unroll
    for (int nt=0; nt<4; ++nt){
      float bias = bf3s[nt*16+c];
#pragma unroll
      for (int q=0; q<4; ++q){
        float t = acc3[nt][q] + bias; v[nt][q] = t > 0.f ? t : 0.f;
      }
    }
#pragma unroll
    for (int q=0; q<4; ++q){
      int lrow = u*4 + q;
      float p = v[0][q] + v[1][q] + v[2][q] + v[3][q];
      p += __shfl_xor(p, 1); p += __shfl_xor(p, 2); p += __shfl_xor(p, 4); p += __shfl_xor(p, 8);
      float mu = p * 0.015625f;
      float d0 = v[0][q]-mu, d1 = v[1][q]-mu, d2 = v[2][q]-mu, d3 = v[3][q]-mu;
      float p2 = d0*d0 + d1*d1 + d2*d2 + d3*d3;
      p2 += __shfl_xor(p2, 1); p2 += __shfl_xor(p2, 2); p2 += __shfl_xor(p2, 4); p2 += __shfl_xor(p2, 8);
      float rstd = __builtin_amdgcn_rsqf(p2 * 0.015625f + 1e-5f);
      if (lrow < 8){
        int row = rowb + lrow;
#pragma unroll
        for (int nt=0; nt<4; ++nt){
          int col = nt*16 + c;
          out[(size_t)row*64 + col] = (v[nt][q] - mu) * rstd * lngs[col] + lnbs[col];
        }
      }
    }
  }
}

extern "C" void kernel_launch(void* const* d_in, const int* in_sizes, int n_in,
                              void* d_out, int out_size, void* d_ws, size_t ws_size,
                              hipStream_t stream)
{
  const float* ttraj = (const float*)d_in[0];
  const float* ntraj = (const float*)d_in[1];
  const float* rang  = (const float*)d_in[2];
  const float* nmask = (const float*)d_in[3];
  const float* Wih_t = (const float*)d_in[4];
  const float* Whh_t = (const float*)d_in[5];
  const float* bih_t = (const float*)d_in[6];
  const float* bhh_t = (const float*)d_in[7];
  const float* Wih_n = (const float*)d_in[8];
  const float* Whh_n = (const float*)d_in[9];
  const float* bih_n = (const float*)d_in[10];
  const float* bhh_n = (const float*)d_in[11];
  const float* W1  = (const float*)d_in[12];
  const float* b1  = (const float*)d_in[13];
  const float* W2  = (const float*)d_in[14];
  const float* b2  = (const float*)d_in[15];
  const float* Wf1 = (const float*)d_in[16];
  const float* bf1 = (const float*)d_in[17];
  const float* Wf2 = (const float*)d_in[18];
  const float* bf2 = (const float*)d_in[19];
  const float* Wf3 = (const float*)d_in[20];
  const float* bf3 = (const float*)d_in[21];
  const float* lng = (const float*)d_in[22];
  const float* lnb = (const float*)d_in[23];

  char* ws = (char*)d_ws;
  unsigned short* combined = (unsigned short*)ws;                  // [2048][1152] bf16
  unsigned short* sf       = (unsigned short*)(ws + 5242880);      // [16384][96] bf16
  unsigned short* wgt      = (unsigned short*)(ws + 8388608);      // bf16 weights (413696 u16)

  hipLaunchKernelGGL(k_gn, dim3(3664), dim3(256), 0, stream,
                     ttraj, ntraj, rang, nmask,
                     Wih_n, bih_n, bhh_n, Whh_n,
                     Whh_t, W1, W2, Wf1, Wf2, Wf3,
                     wgt, sf);
  hipLaunchKernelGGL(k_gt_mlp, dim3(384), dim3(256), 0, stream,
                     ttraj, Wih_t, bih_t, bhh_t, sf, wgt, b1, b2, combined);
  hipLaunchKernelGGL(k_head, dim3(256), dim3(256), 0, stream,
                     combined, wgt, bf1, bf2, bf3, lng, lnb, (float*)d_out);
}